// Round 11
// baseline (861.528 us; speedup 1.0000x reference)
//
#include <hip/hip_runtime.h>
#include <hip/hip_bf16.h>
#include <math.h>

#define S_LEN 4096
#define DIM   1024
#define HID   4096
#define NLAYER 2
#define RDIM  256
#define VOCAB 32000
#define QKVN  768

typedef unsigned short u16;
typedef __attribute__((ext_vector_type(8))) short s16x8;
typedef __attribute__((ext_vector_type(4))) float f32x4;
typedef __attribute__((ext_vector_type(4))) unsigned short u16x4;

__device__ inline u16 f2b(float f){
  unsigned u = __float_as_uint(f);
  u += 0x7fff + ((u >> 16) & 1);   // RNE
  return (u16)(u >> 16);
}

__device__ inline void gload_lds16(const void* g, void* l){
  __builtin_amdgcn_global_load_lds((__attribute__((address_space(1))) void*)(g),
                                   (__attribute__((address_space(3))) void*)(l), 16, 0, 0);
}

// ======== mega-prep: all weight transposes (f32 [K][N] -> bf16 [N][K]) ========
// + qkv bias concat, in ONE launch. All job dims compile-time; blockIdx decode.
// blocks 0..5: bias concat (2 layers x 3 chunks of 256)
// then 64x64 transpose tiles: Wg 512 | Ws 2048 | Wo 2048 | Wq 128 | Wk 128 |
// Wv 128 | Wao 128 | outW 8000   (total 13126 blocks, 256 threads)
__global__ void k_prep(const float* __restrict__ Wg,  const float* __restrict__ Ws,
                       const float* __restrict__ Wo,  const float* __restrict__ Wq,
                       const float* __restrict__ Wk,  const float* __restrict__ Wv,
                       const float* __restrict__ Wao, const float* __restrict__ outW,
                       u16* __restrict__ WgT, u16* __restrict__ WsT, u16* __restrict__ WoT,
                       u16* __restrict__ WqkvT, u16* __restrict__ WaoT, u16* __restrict__ outWT,
                       const float* __restrict__ bq, const float* __restrict__ bk,
                       const float* __restrict__ bv, float* __restrict__ bqkv2){
  __shared__ float tile[64][65];
  int tx = threadIdx.x, ty = threadIdx.y;   // (16,16)
  int id = blockIdx.x;
  if (id < 6){
    int t = ty * 16 + tx;
    int l = id / 3, sel = id % 3;
    const float* s = sel == 0 ? bq : (sel == 1 ? bk : bv);
    bqkv2[l * 768 + sel * 256 + t] = s[(size_t)l * 256 + t];
    return;
  }
  id -= 6;
  const float* src; u16* dst; int K, N, bx, by;
  if (id < 512){            // Wg [1024][1024] x2
    int z = id >> 8, lo = id & 255;
    src = Wg + (size_t)z * DIM * DIM; dst = WgT + (size_t)z * DIM * DIM;
    K = DIM; N = DIM; bx = lo & 15; by = lo >> 4;
  } else if (id < 2560){    // Ws [1024][4096] x2
    int local = id - 512; int z = local >> 10, lo = local & 1023;
    src = Ws + (size_t)z * DIM * HID; dst = WsT + (size_t)z * DIM * HID;
    K = DIM; N = HID; bx = lo & 63; by = lo >> 6;
  } else if (id < 4608){    // Wo [4096][1024] x2
    int local = id - 2560; int z = local >> 10, lo = local & 1023;
    src = Wo + (size_t)z * HID * DIM; dst = WoT + (size_t)z * HID * DIM;
    K = HID; N = DIM; bx = lo & 15; by = lo >> 4;
  } else if (id < 4736){    // Wq [1024][256] x2
    int local = id - 4608; int z = local >> 6, lo = local & 63;
    src = Wq + (size_t)z * DIM * RDIM; dst = WqkvT + (size_t)z * QKVN * DIM;
    K = DIM; N = RDIM; bx = lo & 3; by = lo >> 2;
  } else if (id < 4864){    // Wk
    int local = id - 4736; int z = local >> 6, lo = local & 63;
    src = Wk + (size_t)z * DIM * RDIM; dst = WqkvT + (size_t)z * QKVN * DIM + (size_t)256 * DIM;
    K = DIM; N = RDIM; bx = lo & 3; by = lo >> 2;
  } else if (id < 4992){    // Wv
    int local = id - 4864; int z = local >> 6, lo = local & 63;
    src = Wv + (size_t)z * DIM * RDIM; dst = WqkvT + (size_t)z * QKVN * DIM + (size_t)512 * DIM;
    K = DIM; N = RDIM; bx = lo & 3; by = lo >> 2;
  } else if (id < 5120){    // Wao [256][1024] x2
    int local = id - 4992; int z = local >> 6, lo = local & 63;
    src = Wao + (size_t)z * RDIM * DIM; dst = WaoT + (size_t)z * RDIM * DIM;
    K = RDIM; N = DIM; bx = lo & 15; by = lo >> 4;
  } else {                  // outW [1024][32000]
    int local = id - 5120;
    src = outW; dst = outWT;
    K = DIM; N = VOCAB; bx = local % 500; by = local / 500;
  }
  int n0 = bx * 64, k0 = by * 64;
  #pragma unroll
  for (int i = 0; i < 4; i++){
    float4 v = *(const float4*)&src[(size_t)(k0 + ty + 16 * i) * N + n0 + tx * 4];
    tile[ty + 16 * i][tx * 4 + 0] = v.x;
    tile[ty + 16 * i][tx * 4 + 1] = v.y;
    tile[ty + 16 * i][tx * 4 + 2] = v.z;
    tile[ty + 16 * i][tx * 4 + 3] = v.w;
  }
  __syncthreads();
  #pragma unroll
  for (int i = 0; i < 4; i++){
    u16x4 o;
    #pragma unroll
    for (int j = 0; j < 4; j++) o[j] = f2b(tile[tx * 4 + j][ty + 16 * i]);
    *(u16x4*)&dst[(size_t)(n0 + ty + 16 * i) * K + k0 + tx * 4] = o;
  }
}

// -------- embedding gather + positional + decay accumulation ------------------
__global__ void k_embed(const int* __restrict__ idx, const float* __restrict__ emb,
                        const float* __restrict__ pos, float* __restrict__ xf,
                        u16* __restrict__ xb){
  int s = blockIdx.x;
  int d = blockIdx.y * 256 + threadIdx.x;
  float v = emb[(size_t)idx[s] * DIM + d] + pos[(size_t)s * DIM + d];
  if (s > 0){
    float x0 = emb[(size_t)idx[0] * DIM + d] + pos[d];
    v += exp2f((float)s * -0.3219280948873623f) * x0;  // 0.8^s
  }
  size_t o = (size_t)s * DIM + d;
  xf[o] = v; xb[o] = f2b(v);
}

#define EP_GATE  0
#define EP_TANH  1
#define EP_RESID 2
#define EP_BIASF 3
#define EP_AO    4
#define EP_OUT   5

#define PH_SYNC() do{ asm volatile("" ::: "memory"); __builtin_amdgcn_s_barrier(); asm volatile("" ::: "memory"); }while(0)

// ============ 256x256 8-phase PERSISTENT GEMM (logits) ========================
// Verified template + persistence with CONTIGUOUS chunk walk (this round):
// block b owns tiles [b*nT/G, (b+1)*nT/G) in 2-bm-stripe bn-fastest order ->
// A ping-pongs between 2 L2-hot panels, B advances every 2 tiles, and the 8
// concurrent stripe-groups share each B panel through L3 (fetch ~= B once).

#define MMA_QUAD(MH, NLO, BF) \
  { _Pragma("unroll") for (int mi = 0; mi < 4; mi++){ \
    _Pragma("unroll") for (int ni = 0; ni < 2; ni++){ \
      _Pragma("unroll") for (int ks = 0; ks < 2; ks++){ \
        acc[(MH)*4+mi][(NLO)+ni] = __builtin_amdgcn_mfma_f32_16x16x32_bf16((BF)[ni*2+ks], af[mi*2+ks], acc[(MH)*4+mi][(NLO)+ni], 0, 0, 0); } } } }

#define LDA(MH, BO) \
  { _Pragma("unroll") for (int mi = 0; mi < 4; mi++){ \
    _Pragma("unroll") for (int ks = 0; ks < 2; ks++){ \
      af[mi*2+ks] = *(const s16x8*)(pa0 + (BO) + ((MH)*4+mi)*1024 + ((ks ^ kb) * 32)); } } }

#define LDB(NH, BO) \
  { _Pragma("unroll") for (int ni = 0; ni < 2; ni++){ \
    _Pragma("unroll") for (int ks = 0; ks < 2; ks++){ \
      bf_[(NH)*4+ni*2+ks] = *(const s16x8*)(pb0 + (BO) + ((NH)*2+ni)*1024 + ((ks ^ kb) * 32)); } } }

__global__ __launch_bounds__(512, 2) void k_gemmL(
    const u16* __restrict__ A, const u16* __restrict__ Bt,
    const float* __restrict__ bias, float* __restrict__ outf,
    int N, int K, int tilesM, int tilesN){
  extern __shared__ u16 lds[];   // [A: 2x16384][B at 32768: 2x16384] u16
  const int t = threadIdx.x;
  const int w = t >> 6, l = t & 63;
  const int wr = w >> 2, wc = w & 3;
  const int NT = K >> 6;
  const int NI = NT >> 1;
  const int nTiles = tilesM * tilesN;

  const int r0 = t >> 3;
  const int scol = (((t & 7) ^ ((t >> 3) & 7)) * 8);
  const int cb = (((l >> 4) ^ (l & 3)) * 8);
  const int kb = (l >> 2) & 1;
  const u16* pa0 = lds + (wr * 128 + (l & 15)) * 64 + cb;
  const u16* pb0 = lds + 32768 + (wc * 64 + (l & 15)) * 64 + cb;

  // 2-bm stripes, bn fastest within the stripe
  auto decode = [&](int idx, int& bR, int& bC){
    int pr = tilesN * 2;
    int stripe = idx / pr, r2 = idx % pr;
    bR = (stripe * 2 + (r2 & 1)) * 256;
    bC = (r2 >> 1) * 256;
  };

  // contiguous chunk for this block
  int startT = (int)(((long long)blockIdx.x * nTiles) / gridDim.x);
  int endT   = (int)(((long long)(blockIdx.x + 1) * nTiles) / gridDim.x);
  if (startT >= endT) return;
  int tileIdx = startT;
  int bRow, bCol, nRow = 0, nCol = 0;
  bool hasNext = false;
  decode(tileIdx, bRow, bCol);

  auto stage_half = [&](int tau, int q){                    // q: 0=A.h0 1=A.h1 2=B.h0 3=B.h1
    const u16* base;
    if (tau >= NT){
      if (!hasNext) return;
      tau -= NT;
      base = (q < 2) ? A + (size_t)nRow * K : Bt + (size_t)nCol * K;
    } else {
      base = (q < 2) ? A + (size_t)bRow * K : Bt + (size_t)bCol * K;
    }
    int h = q & 1;
    const u16* gp = base + (size_t)(h * 128 + r0) * K + (size_t)tau * 64 + scol;
    u16* d = lds + ((q < 2) ? 0 : 32768) + ((tau & 1) * 16384) + h * 8192 + t * 8;
    gload_lds16(gp, d);
    gload_lds16(gp + (size_t)64 * K, d + 4096);
  };

  f32x4 acc[8][4] = {};
  s16x8 af[8], bf_[8];

  // prologue (once): tile-0 complete + tile-1 half A0; leave 2 in flight
  stage_half(0, 0); stage_half(0, 1); stage_half(0, 2); stage_half(0, 3);
  stage_half(1, 0);
  asm volatile("s_waitcnt vmcnt(2)" ::: "memory");
  PH_SYNC();

  for (; tileIdx < endT; ++tileIdx){
    hasNext = (tileIdx + 1) < endT;
    if (hasNext) decode(tileIdx + 1, nRow, nCol);

    for (int i = 0; i < NI; i++){
      const int t1 = 2 * i + 1, t2 = 2 * i + 2, t3 = 2 * i + 3;
      const bool lastGate = (!hasNext) && (i + 1 == NI);
      // ---- K-tile 2i (buf0) ----
      LDA(0, 0); LDB(0, 0);
      stage_half(t1, 1);
      PH_SYNC();
      __builtin_amdgcn_s_setprio(1); MMA_QUAD(0, 0, bf_); __builtin_amdgcn_s_setprio(0);
      PH_SYNC();
      LDB(1, 0);
      stage_half(t1, 2);
      PH_SYNC();
      __builtin_amdgcn_s_setprio(1); MMA_QUAD(0, 2, bf_ + 4); __builtin_amdgcn_s_setprio(0);
      PH_SYNC();
      LDA(1, 0);
      stage_half(t1, 3);
      PH_SYNC();
      __builtin_amdgcn_s_setprio(1); MMA_QUAD(1, 2, bf_ + 4); __builtin_amdgcn_s_setprio(0);
      PH_SYNC();
      stage_half(t2, 0);
      if (!lastGate) asm volatile("s_waitcnt vmcnt(2)" ::: "memory");
      else           asm volatile("s_waitcnt vmcnt(0)" ::: "memory");
      PH_SYNC();
      __builtin_amdgcn_s_setprio(1); MMA_QUAD(1, 0, bf_); __builtin_amdgcn_s_setprio(0);
      PH_SYNC();
      // ---- K-tile 2i+1 (buf1) ----
      LDA(0, 16384); LDB(0, 16384);
      stage_half(t2, 1);
      PH_SYNC();
      __builtin_amdgcn_s_setprio(1); MMA_QUAD(0, 0, bf_); __builtin_amdgcn_s_setprio(0);
      PH_SYNC();
      LDB(1, 16384);
      stage_half(t2, 2);
      PH_SYNC();
      __builtin_amdgcn_s_setprio(1); MMA_QUAD(0, 2, bf_ + 4); __builtin_amdgcn_s_setprio(0);
      PH_SYNC();
      LDA(1, 16384);
      stage_half(t2, 3);
      PH_SYNC();
      __builtin_amdgcn_s_setprio(1); MMA_QUAD(1, 2, bf_ + 4); __builtin_amdgcn_s_setprio(0);
      PH_SYNC();
      stage_half(t3, 0);
      if (!lastGate) asm volatile("s_waitcnt vmcnt(2)" ::: "memory");
      PH_SYNC();
      __builtin_amdgcn_s_setprio(1); MMA_QUAD(1, 0, bf_); __builtin_amdgcn_s_setprio(0);
      PH_SYNC();
    }

    // epilogue (swapped D): row(M) = l&15, col(N) = (l>>4)*4 + q
    #pragma unroll
    for (int m = 0; m < 8; m++){
      int gr = bRow + wr * 128 + m * 16 + (l & 15);
      #pragma unroll
      for (int n = 0; n < 4; n++){
        int gc = bCol + wc * 64 + n * 16 + ((l >> 4) * 4);
        f32x4 v = acc[m][n] + *(const f32x4*)(bias + gc);
        *(f32x4*)(outf + (size_t)gr * N + gc) = v;
        acc[m][n] = (f32x4){0.f, 0.f, 0.f, 0.f};
      }
    }
    bRow = nRow; bCol = nCol;
  }
}

// ============ 128x128 8-phase GEMM, BK=64, 8 waves, 2 blocks/CU ===============
// Round-5/6-verified schedule; carries all layer epilogues.

#define MMA2(MH, NL) \
  { _Pragma("unroll") for (int mi = 0; mi < 2; mi++){ \
    _Pragma("unroll") for (int ks = 0; ks < 2; ks++){ \
      acc[(MH)*2+mi][(NL)] = __builtin_amdgcn_mfma_f32_16x16x32_bf16(bf_[(NL)*2+ks], af[mi*2+ks], acc[(MH)*2+mi][(NL)], 0, 0, 0); } } }

#define LDA2(MH, BO) \
  { _Pragma("unroll") for (int mi = 0; mi < 2; mi++){ \
    _Pragma("unroll") for (int ks = 0; ks < 2; ks++){ \
      af[mi*2+ks] = *(const s16x8*)(pa0 + (BO) + ((MH)*2+mi)*1024 + ((ks ^ kb) * 32)); } } }

#define LDB2(NL, BO) \
  { _Pragma("unroll") for (int ks = 0; ks < 2; ks++){ \
    bf_[(NL)*2+ks] = *(const s16x8*)(pb0 + (BO) + (NL)*1024 + ((ks ^ kb) * 32)); } }

template<int EPI>
__global__ __launch_bounds__(512, 4) void k_gemm8b(
    const u16* __restrict__ A, const u16* __restrict__ Bt,
    const float* __restrict__ bias, const float* __restrict__ aux,
    float* __restrict__ outf, u16* __restrict__ outbf,
    int N, int K, int tilesM, int tilesN){
  extern __shared__ u16 lds[];   // [A: 2buf x 8192][B at 16384: 2buf x 8192] u16
  const int t = threadIdx.x;
  const int w = t >> 6, l = t & 63;
  const int wr = w >> 2, wc = w & 3;     // 2M x 4N waves; wave out 64x32
  const int NT = K >> 6;
  const int NI = NT >> 1;

  int nwg = tilesM * tilesN;
  int id = blockIdx.x, id2;
  if ((nwg & 7) == 0){ int c = nwg >> 3; id2 = (id & 7) * c + (id >> 3); }
  else id2 = id;
  int per = tilesM << 3;
  int g = id2 / per, r = id2 % per;
  int bm = r % tilesM;
  int bn = (g << 3) + r / tilesM;
  const int bRow = bm * 128, bCol = bn * 128;

  const int r0 = t >> 3;
  const int scol = (((t & 7) ^ ((t >> 3) & 7)) * 8);

  auto stage_half = [&](int tau, int q){   // q: 0=A.h0 1=A.h1 2=B.h0 3=B.h1
    if (tau >= NT) return;
    int h = q & 1;
    bool isA = q < 2;
    const u16* gp = (isA ? A + (size_t)bRow * K : Bt + (size_t)bCol * K)
                 + (size_t)(h * 64 + r0) * K + (size_t)tau * 64 + scol;
    u16* d = lds + (isA ? 0 : 16384) + ((tau & 1) * 8192) + h * 4096 + t * 8;
    gload_lds16(gp, d);
  };

  const int cb = (((l >> 4) ^ (l & 3)) * 8);
  const int kb = (l >> 2) & 1;
  const u16* pa0 = lds + wr * 4096 + (l & 15) * 64 + cb;
  const u16* pb0 = lds + 16384 + (wc >> 1) * 4096 + ((wc & 1) * 32 + (l & 15)) * 64 + cb;

  f32x4 acc[4][2] = {};
  s16x8 af[4], bf_[4];

  stage_half(0, 0); stage_half(0, 1); stage_half(0, 2); stage_half(0, 3);
  stage_half(1, 0);
  asm volatile("s_waitcnt vmcnt(1)" ::: "memory");
  PH_SYNC();

  for (int i = 0; i < NI; i++){
    const int t1 = 2 * i + 1, t2 = 2 * i + 2, t3 = 2 * i + 3;
    const bool last = (i + 1 == NI);
    // ---- K-tile 2i (buf0) ----
    LDA2(0, 0); LDB2(0, 0);
    stage_half(t1, 1);
    PH_SYNC();
    __builtin_amdgcn_s_setprio(1); MMA2(0, 0); __builtin_amdgcn_s_setprio(0);
    PH_SYNC();
    LDB2(1, 0);
    stage_half(t1, 2);
    PH_SYNC();
    __builtin_amdgcn_s_setprio(1); MMA2(0, 1); __builtin_amdgcn_s_setprio(0);
    PH_SYNC();
    LDA2(1, 0);
    stage_half(t1, 3);
    PH_SYNC();
    __builtin_amdgcn_s_setprio(1); MMA2(1, 1); __builtin_amdgcn_s_setprio(0);
    PH_SYNC();
    stage_half(t2, 0);
    if (!last) asm volatile("s_waitcnt vmcnt(1)" ::: "memory");
    else       asm volatile("s_waitcnt vmcnt(0)" ::: "memory");
    PH_SYNC();
    __builtin_amdgcn_s_setprio(1); MMA2(1, 0); __builtin_amdgcn_s_setprio(0);
    PH_SYNC();
    // ---- K-tile 2i+1 (buf1) ----
    LDA2(0, 8192); LDB2(0, 8192);
    stage_half(t2, 1);
    PH_SYNC();
    __builtin_amdgcn_s_setprio(1); MMA2(0, 0); __builtin_amdgcn_s_setprio(0);
    PH_SYNC();
    LDB2(1, 8192);
    stage_half(t2, 2);
    PH_SYNC();
    __builtin_amdgcn_s_setprio(1); MMA2(0, 1); __builtin_amdgcn_s_setprio(0);
    PH_SYNC();
    LDA2(1, 8192);
    stage_half(t2, 3);
    PH_SYNC();
    __builtin_amdgcn_s_setprio(1); MMA2(1, 1); __builtin_amdgcn_s_setprio(0);
    PH_SYNC();
    stage_half(t3, 0);
    if (!last) asm volatile("s_waitcnt vmcnt(1)" ::: "memory");
    PH_SYNC();
    __builtin_amdgcn_s_setprio(1); MMA2(1, 0); __builtin_amdgcn_s_setprio(0);
    PH_SYNC();
  }

  // epilogue (swapped D): row(M) = l&15, col(N) = (l>>4)*4 + q
  #pragma unroll
  for (int m = 0; m < 4; m++){
    int gr = bRow + wr * 64 + m * 16 + (l & 15);
    #pragma unroll
    for (int n = 0; n < 2; n++){
      int gc = bCol + wc * 32 + n * 16 + ((l >> 4) * 4);
      size_t o = (size_t)gr * N + gc;
      f32x4 v = acc[m][n] + *(const f32x4*)(bias + gc);
      if constexpr (EPI == EP_GATE){
        f32x4 a = *(const f32x4*)(aux + o);
        u16x4 rr;
        #pragma unroll
        for (int q = 0; q < 4; q++) rr[q] = f2b(a[q] / (1.f + expf(-v[q])));
        *(u16x4*)(outbf + o) = rr;
      } else if constexpr (EPI == EP_TANH){
        u16x4 rr;
        #pragma unroll
        for (int q = 0; q < 4; q++) rr[q] = f2b(tanhf(v[q]));
        *(u16x4*)(outbf + o) = rr;
      } else if constexpr (EPI == EP_RESID){
        v += *(const f32x4*)(aux + o);
        *(f32x4*)(outf + o) = v;
        u16x4 rr;
        #pragma unroll
        for (int q = 0; q < 4; q++) rr[q] = f2b(v[q]);
        *(u16x4*)(outbf + o) = rr;
      } else if constexpr (EPI == EP_BIASF){
        *(f32x4*)(outf + o) = v;
      } else if constexpr (EPI == EP_AO){
        v += *(const f32x4*)(aux + o);
        *(f32x4*)(outf + o) = v;
      } else {
        *(f32x4*)(outf + o) = v;
      }
    }
  }
}

// -------- windowed attention: 4 tokens per block (1 wave each) ----------------
__global__ void k_attn(const float* __restrict__ qkv, u16* __restrict__ aob){
  int s = blockIdx.x * 4 + (threadIdx.x >> 6);
  int l = threadIdx.x & 63;
  const float* qp = qkv + (size_t)s * QKVN;
  float qr[4];
  #pragma unroll
  for (int r = 0; r < 4; r++) qr[r] = qp[l + 64 * r];
  float sc[9];
  float mx = -1e30f;
  #pragma unroll
  for (int j = 0; j <= 8; j++){
    int sj = s - j;
    bool ok = sj >= 0;
    int row = ok ? sj : 0;
    const float* kp = qkv + (size_t)row * QKVN + RDIM;
    float p = 0.f;
    #pragma unroll
    for (int r = 0; r < 4; r++) p += qr[r] * kp[l + 64 * r];
    #pragma unroll
    for (int off = 32; off; off >>= 1) p += __shfl_xor(p, off);
    p = ok ? p * 0.0625f : -1e30f;   // /sqrt(256)
    sc[j] = p;
    mx = fmaxf(mx, p);
  }
  float den = 0.f;
  #pragma unroll
  for (int j = 0; j <= 8; j++){ sc[j] = expf(sc[j] - mx); den += sc[j]; }
  float inv = 1.f / den;
  #pragma unroll
  for (int r = 0; r < 4; r++){
    float a = 0.f;
    #pragma unroll
    for (int j = 0; j <= 8; j++){
      int sj = s - j;
      int row = sj >= 0 ? sj : 0;
      a += sc[j] * qkv[(size_t)row * QKVN + 512 + l + 64 * r];
    }
    aob[(size_t)s * RDIM + l + 64 * r] = f2b(a * inv);
  }
}

// -------- chunk link ----------------------------------------------------------
__global__ void k_chunk(const float* __restrict__ xin, float* __restrict__ xout,
                        u16* __restrict__ xb){
  int s = blockIdx.x;
  int d = blockIdx.y * 256 + threadIdx.x;
  int ci = s >> 6;
  float v = xin[(size_t)s * DIM + d];
  float wsum = 1.f;
  if (ci > 0){ v += 0.5f * xin[(size_t)(s - 64) * DIM + d]; wsum += 0.5f; }
  if (ci < 63){ v += 0.5f * xin[(size_t)(s + 64) * DIM + d]; wsum += 0.5f; }
  v /= wsum;
  size_t o = (size_t)s * DIM + d;
  xout[o] = v; xb[o] = f2b(v);
}

extern "C" void kernel_launch(void* const* d_in, const int* in_sizes, int n_in,
                              void* d_out, int out_size, void* d_ws, size_t ws_size,
                              hipStream_t stream){
  const int*   idx  = (const int*)d_in[0];
  const float* emb  = (const float*)d_in[1];
  const float* pos  = (const float*)d_in[2];
  const float* Wg   = (const float*)d_in[3];
  const float* bg   = (const float*)d_in[4];
  const float* Ws_  = (const float*)d_in[5];
  const float* bs   = (const float*)d_in[6];
  const float* Wo   = (const float*)d_in[7];
  const float* bo   = (const float*)d_in[8];
  const float* Wq   = (const float*)d_in[9];
  const float* Wk   = (const float*)d_in[10];
  const float* Wv   = (const float*)d_in[11];
  const float* Wao  = (const float*)d_in[12];
  const float* bq   = (const float*)d_in[13];
  const float* bk   = (const float*)d_in[14];
  const float* bv   = (const float*)d_in[15];
  const float* bao  = (const float*)d_in[16];
  const float* outW = (const float*)d_in[17];
  const float* outb = (const float*)d_in[18];
  float* out = (float*)d_out;

  char* p = (char*)d_ws;
  auto alloc = [&](size_t n)->char*{ char* r = p; p += (n + 255) & ~(size_t)255; return r; };
  float* xfA  = (float*)alloc((size_t)S_LEN * DIM * 4);
  float* xfB  = (float*)alloc((size_t)S_LEN * DIM * 4);
  u16*   xb   = (u16*)  alloc((size_t)S_LEN * DIM * 2);
  u16*   xgb  = (u16*)  alloc((size_t)S_LEN * DIM * 2);
  u16*   tbuf = (u16*)  alloc((size_t)S_LEN * HID * 2);
  float* qkvf = (float*)alloc((size_t)S_LEN * QKVN * 4);
  u16*   aob  = (u16*)  alloc((size_t)S_LEN * RDIM * 2);
  float* bqkv2= (float*)alloc(2 * QKVN * 4);
  u16*   WgT  = (u16*)  alloc((size_t)NLAYER * DIM * DIM * 2);
  u16*   WsT  = (u16*)  alloc((size_t)NLAYER * DIM * HID * 2);
  u16*   WoT  = (u16*)  alloc((size_t)NLAYER * HID * DIM * 2);
  u16*   WqkvT= (u16*)  alloc((size_t)NLAYER * QKVN * DIM * 2);
  u16*   WaoT = (u16*)  alloc((size_t)NLAYER * RDIM * DIM * 2);
  u16*   outWT= (u16*)  alloc((size_t)VOCAB * DIM * 2);

  (void)hipFuncSetAttribute((const void*)&k_gemmL,
                      hipFuncAttributeMaxDynamicSharedMemorySize, 131072);
  (void)hipFuncSetAttribute((const void*)&k_gemm8b<EP_GATE>,
                      hipFuncAttributeMaxDynamicSharedMemorySize, 65536);
  (void)hipFuncSetAttribute((const void*)&k_gemm8b<EP_TANH>,
                      hipFuncAttributeMaxDynamicSharedMemorySize, 65536);
  (void)hipFuncSetAttribute((const void*)&k_gemm8b<EP_RESID>,
                      hipFuncAttributeMaxDynamicSharedMemorySize, 65536);
  (void)hipFuncSetAttribute((const void*)&k_gemm8b<EP_BIASF>,
                      hipFuncAttributeMaxDynamicSharedMemorySize, 65536);
  (void)hipFuncSetAttribute((const void*)&k_gemm8b<EP_AO>,
                      hipFuncAttributeMaxDynamicSharedMemorySize, 65536);

  // one prep launch: all transposes + qkv bias concats
  k_prep<<<13126, dim3(16, 16), 0, stream>>>(Wg, Ws_, Wo, Wq, Wk, Wv, Wao, outW,
                                             WgT, WsT, WoT, WqkvT, WaoT, outWT,
                                             bq, bk, bv, bqkv2);

  k_embed<<<dim3(S_LEN, DIM/256), 256, 0, stream>>>(idx, emb, pos, xfA, xb);

  float* curF = xfA; float* altF = xfB;
  for (int l = 0; l < NLAYER; l++){
    k_gemm8b<EP_GATE ><<<(S_LEN/128)*(DIM/128),  512, 65536, stream>>>(xb,  WgT  + (size_t)l*DIM*DIM,  bg + (size_t)l*DIM, curF, nullptr, xgb, DIM, DIM, S_LEN/128, DIM/128);
    k_gemm8b<EP_TANH ><<<(S_LEN/128)*(HID/128),  512, 65536, stream>>>(xgb, WsT  + (size_t)l*DIM*HID,  bs + (size_t)l*HID, nullptr, nullptr, tbuf, HID, DIM, S_LEN/128, HID/128);
    k_gemm8b<EP_RESID><<<(S_LEN/128)*(DIM/128),  512, 65536, stream>>>(tbuf,WoT  + (size_t)l*HID*DIM,  bo + (size_t)l*DIM, curF, curF, xb, DIM, HID, S_LEN/128, DIM/128);
    k_gemm8b<EP_BIASF><<<(S_LEN/128)*(QKVN/128), 512, 65536, stream>>>(xb,  WqkvT + (size_t)l*QKVN*DIM, bqkv2 + (size_t)l*QKVN, nullptr, qkvf, nullptr, QKVN, DIM, S_LEN/128, QKVN/128);
    k_attn<<<S_LEN/4, 256, 0, stream>>>(qkvf, aob);
    k_gemm8b<EP_AO   ><<<(S_LEN/128)*(DIM/128),  512, 65536, stream>>>(aob, WaoT + (size_t)l*RDIM*DIM, bao + (size_t)l*DIM, curF, curF, nullptr, DIM, RDIM, S_LEN/128, DIM/128);
    k_chunk<<<dim3(S_LEN, DIM/256), 256, 0, stream>>>(curF, altF, xb);
    float* tmp = curF; curF = altF; altF = tmp;
  }
  k_gemmL<<<256, 512, 131072, stream>>>(xb, outWT, outb, out, VOCAB, DIM, S_LEN/256, VOCAB/256);
}

// Round 12
// 839.924 us; speedup vs baseline: 1.0257x; 1.0257x over previous
//
#include <hip/hip_runtime.h>
#include <hip/hip_bf16.h>
#include <math.h>

#define S_LEN 4096
#define DIM   1024
#define HID   4096
#define NLAYER 2
#define RDIM  256
#define VOCAB 32000
#define QKVN  768

typedef unsigned short u16;
typedef __attribute__((ext_vector_type(8))) short s16x8;
typedef __attribute__((ext_vector_type(4))) float f32x4;
typedef __attribute__((ext_vector_type(4))) unsigned short u16x4;

__device__ inline u16 f2b(float f){
  unsigned u = __float_as_uint(f);
  u += 0x7fff + ((u >> 16) & 1);   // RNE
  return (u16)(u >> 16);
}

__device__ inline void gload_lds16(const void* g, void* l){
  __builtin_amdgcn_global_load_lds((__attribute__((address_space(1))) void*)(g),
                                   (__attribute__((address_space(3))) void*)(l), 16, 0, 0);
}

// ======== mega-prep: all weight transposes (f32 [K][N] -> bf16 [N][K]) ========
__global__ void k_prep(const float* __restrict__ Wg,  const float* __restrict__ Ws,
                       const float* __restrict__ Wo,  const float* __restrict__ Wq,
                       const float* __restrict__ Wk,  const float* __restrict__ Wv,
                       const float* __restrict__ Wao, const float* __restrict__ outW,
                       u16* __restrict__ WgT, u16* __restrict__ WsT, u16* __restrict__ WoT,
                       u16* __restrict__ WqkvT, u16* __restrict__ WaoT, u16* __restrict__ outWT,
                       const float* __restrict__ bq, const float* __restrict__ bk,
                       const float* __restrict__ bv, float* __restrict__ bqkv2){
  __shared__ float tile[64][65];
  int tx = threadIdx.x, ty = threadIdx.y;   // (16,16)
  int id = blockIdx.x;
  if (id < 6){
    int t = ty * 16 + tx;
    int l = id / 3, sel = id % 3;
    const float* s = sel == 0 ? bq : (sel == 1 ? bk : bv);
    bqkv2[l * 768 + sel * 256 + t] = s[(size_t)l * 256 + t];
    return;
  }
  id -= 6;
  const float* src; u16* dst; int K, N, bx, by;
  if (id < 512){
    int z = id >> 8, lo = id & 255;
    src = Wg + (size_t)z * DIM * DIM; dst = WgT + (size_t)z * DIM * DIM;
    K = DIM; N = DIM; bx = lo & 15; by = lo >> 4;
  } else if (id < 2560){
    int local = id - 512; int z = local >> 10, lo = local & 1023;
    src = Ws + (size_t)z * DIM * HID; dst = WsT + (size_t)z * DIM * HID;
    K = DIM; N = HID; bx = lo & 63; by = lo >> 6;
  } else if (id < 4608){
    int local = id - 2560; int z = local >> 10, lo = local & 1023;
    src = Wo + (size_t)z * HID * DIM; dst = WoT + (size_t)z * HID * DIM;
    K = HID; N = DIM; bx = lo & 15; by = lo >> 4;
  } else if (id < 4736){
    int local = id - 4608; int z = local >> 6, lo = local & 63;
    src = Wq + (size_t)z * DIM * RDIM; dst = WqkvT + (size_t)z * QKVN * DIM;
    K = DIM; N = RDIM; bx = lo & 3; by = lo >> 2;
  } else if (id < 4864){
    int local = id - 4736; int z = local >> 6, lo = local & 63;
    src = Wk + (size_t)z * DIM * RDIM; dst = WqkvT + (size_t)z * QKVN * DIM + (size_t)256 * DIM;
    K = DIM; N = RDIM; bx = lo & 3; by = lo >> 2;
  } else if (id < 4992){
    int local = id - 4864; int z = local >> 6, lo = local & 63;
    src = Wv + (size_t)z * DIM * RDIM; dst = WqkvT + (size_t)z * QKVN * DIM + (size_t)512 * DIM;
    K = DIM; N = RDIM; bx = lo & 3; by = lo >> 2;
  } else if (id < 5120){
    int local = id - 4992; int z = local >> 6, lo = local & 63;
    src = Wao + (size_t)z * RDIM * DIM; dst = WaoT + (size_t)z * RDIM * DIM;
    K = RDIM; N = DIM; bx = lo & 15; by = lo >> 4;
  } else {
    int local = id - 5120;
    src = outW; dst = outWT;
    K = DIM; N = VOCAB; bx = local % 500; by = local / 500;
  }
  int n0 = bx * 64, k0 = by * 64;
  #pragma unroll
  for (int i = 0; i < 4; i++){
    float4 v = *(const float4*)&src[(size_t)(k0 + ty + 16 * i) * N + n0 + tx * 4];
    tile[ty + 16 * i][tx * 4 + 0] = v.x;
    tile[ty + 16 * i][tx * 4 + 1] = v.y;
    tile[ty + 16 * i][tx * 4 + 2] = v.z;
    tile[ty + 16 * i][tx * 4 + 3] = v.w;
  }
  __syncthreads();
  #pragma unroll
  for (int i = 0; i < 4; i++){
    u16x4 o;
    #pragma unroll
    for (int j = 0; j < 4; j++) o[j] = f2b(tile[tx * 4 + j][ty + 16 * i]);
    *(u16x4*)&dst[(size_t)(n0 + ty + 16 * i) * K + k0 + tx * 4] = o;
  }
}

// -------- embedding gather + positional + decay accumulation ------------------
__global__ void k_embed(const int* __restrict__ idx, const float* __restrict__ emb,
                        const float* __restrict__ pos, float* __restrict__ xf,
                        u16* __restrict__ xb){
  int s = blockIdx.x;
  int d = blockIdx.y * 256 + threadIdx.x;
  float v = emb[(size_t)idx[s] * DIM + d] + pos[(size_t)s * DIM + d];
  if (s > 0){
    float x0 = emb[(size_t)idx[0] * DIM + d] + pos[d];
    v += exp2f((float)s * -0.3219280948873623f) * x0;  // 0.8^s
  }
  size_t o = (size_t)s * DIM + d;
  xf[o] = v; xb[o] = f2b(v);
}

#define EP_GATE  0
#define EP_TANH  1
#define EP_RESID 2
#define EP_BIASF 3
#define EP_AO    4
#define EP_OUT   5

#define PH_SYNC() do{ asm volatile("" ::: "memory"); __builtin_amdgcn_s_barrier(); asm volatile("" ::: "memory"); }while(0)

// ============ 256x256 8-phase PERSISTENT GEMM (logits) ========================
// Verified template + stride-256 persistent walk (round-10 best) + store-drain
// deferral: at tile transition, next-tau1's remaining halves are staged BEFORE
// the epilogue stores (FIFO-older), so the first post-transition gate can be
// vmcnt(34) -> retires only the 8 tau1 loads, leaving the ~32 stores in flight
// to drain in the background until i=0's p8. Safe for any compiler placement of
// epilogue ops (memory fence pins them after the transition stages; FIFO
// retirement guarantees the gate retires tau1 whenever outstanding > 34).

#define MMA_QUAD(MH, NLO, BF) \
  { _Pragma("unroll") for (int mi = 0; mi < 4; mi++){ \
    _Pragma("unroll") for (int ni = 0; ni < 2; ni++){ \
      _Pragma("unroll") for (int ks = 0; ks < 2; ks++){ \
        acc[(MH)*4+mi][(NLO)+ni] = __builtin_amdgcn_mfma_f32_16x16x32_bf16((BF)[ni*2+ks], af[mi*2+ks], acc[(MH)*4+mi][(NLO)+ni], 0, 0, 0); } } } }

#define LDA(MH, BO) \
  { _Pragma("unroll") for (int mi = 0; mi < 4; mi++){ \
    _Pragma("unroll") for (int ks = 0; ks < 2; ks++){ \
      af[mi*2+ks] = *(const s16x8*)(pa0 + (BO) + ((MH)*4+mi)*1024 + ((ks ^ kb) * 32)); } } }

#define LDB(NH, BO) \
  { _Pragma("unroll") for (int ni = 0; ni < 2; ni++){ \
    _Pragma("unroll") for (int ks = 0; ks < 2; ks++){ \
      bf_[(NH)*4+ni*2+ks] = *(const s16x8*)(pb0 + (BO) + ((NH)*2+ni)*1024 + ((ks ^ kb) * 32)); } } }

__global__ __launch_bounds__(512, 2) void k_gemmL(
    const u16* __restrict__ A, const u16* __restrict__ Bt,
    const float* __restrict__ bias, float* __restrict__ outf,
    int N, int K, int tilesM, int tilesN){
  extern __shared__ u16 lds[];   // [A: 2x16384][B at 32768: 2x16384] u16
  const int t = threadIdx.x;
  const int w = t >> 6, l = t & 63;
  const int wr = w >> 2, wc = w & 3;
  const int NT = K >> 6;
  const int NI = NT >> 1;
  const int nTiles = tilesM * tilesN;

  const int r0 = t >> 3;
  const int scol = (((t & 7) ^ ((t >> 3) & 7)) * 8);
  const int cb = (((l >> 4) ^ (l & 3)) * 8);
  const int kb = (l >> 2) & 1;
  const u16* pa0 = lds + (wr * 128 + (l & 15)) * 64 + cb;
  const u16* pb0 = lds + 32768 + (wc * 64 + (l & 15)) * 64 + cb;

  // 2-bm stripes, bn fastest within the stripe
  auto decode = [&](int idx, int& bR, int& bC){
    int pr = tilesN * 2;
    int stripe = idx / pr, r2 = idx % pr;
    bR = (stripe * 2 + (r2 & 1)) * 256;
    bC = (r2 >> 1) * 256;
  };

  int tileIdx = blockIdx.x;
  if (tileIdx >= nTiles) return;
  int bRow, bCol, nRow = 0, nCol = 0;
  bool hasNext = false;
  bool pre = false;
  decode(tileIdx, bRow, bCol);

  auto stage_half = [&](int tau, int q){                    // q: 0=A.h0 1=A.h1 2=B.h0 3=B.h1
    const u16* base;
    if (tau >= NT){
      if (!hasNext) return;
      tau -= NT;
      base = (q < 2) ? A + (size_t)nRow * K : Bt + (size_t)nCol * K;
    } else {
      base = (q < 2) ? A + (size_t)bRow * K : Bt + (size_t)bCol * K;
    }
    int h = q & 1;
    const u16* gp = base + (size_t)(h * 128 + r0) * K + (size_t)tau * 64 + scol;
    u16* d = lds + ((q < 2) ? 0 : 32768) + ((tau & 1) * 16384) + h * 8192 + t * 8;
    gload_lds16(gp, d);
    gload_lds16(gp + (size_t)64 * K, d + 4096);
  };

  f32x4 acc[8][4] = {};
  s16x8 af[8], bf_[8];

  // prologue (once): tile-0 complete + tile-1 half A0; leave 2 in flight
  stage_half(0, 0); stage_half(0, 1); stage_half(0, 2); stage_half(0, 3);
  stage_half(1, 0);
  asm volatile("s_waitcnt vmcnt(2)" ::: "memory");
  PH_SYNC();

  for (; tileIdx < nTiles; tileIdx += gridDim.x){
    int nIdx = tileIdx + gridDim.x;
    hasNext = nIdx < nTiles;
    if (hasNext) decode(nIdx, nRow, nCol);

    // per-tile bias prefetch (keeps compiler's bias-wait off the store queue)
    f32x4 bv4[4];
    #pragma unroll
    for (int n = 0; n < 4; n++)
      bv4[n] = *(const f32x4*)(bias + bCol + wc * 64 + n * 16 + ((l >> 4) * 4));

    for (int i = 0; i < NI; i++){
      const int t1 = 2 * i + 1, t2 = 2 * i + 2, t3 = 2 * i + 3;
      const bool lastGate = (!hasNext) && (i + 1 == NI);
      const bool skipE = pre && (i == 0);   // tau1.q1-3 pre-staged at transition
      // ---- K-tile 2i (buf0) ----
      LDA(0, 0); LDB(0, 0);
      if (!skipE) stage_half(t1, 1);
      PH_SYNC();
      __builtin_amdgcn_s_setprio(1); MMA_QUAD(0, 0, bf_); __builtin_amdgcn_s_setprio(0);
      PH_SYNC();
      LDB(1, 0);
      if (!skipE) stage_half(t1, 2);
      PH_SYNC();
      __builtin_amdgcn_s_setprio(1); MMA_QUAD(0, 2, bf_ + 4); __builtin_amdgcn_s_setprio(0);
      PH_SYNC();
      LDA(1, 0);
      if (!skipE) stage_half(t1, 3);
      PH_SYNC();
      __builtin_amdgcn_s_setprio(1); MMA_QUAD(1, 2, bf_ + 4); __builtin_amdgcn_s_setprio(0);
      PH_SYNC();
      stage_half(t2, 0);
      if (lastGate)      asm volatile("s_waitcnt vmcnt(0)" ::: "memory");
      else if (skipE)    asm volatile("s_waitcnt vmcnt(34)" ::: "memory");
      else               asm volatile("s_waitcnt vmcnt(2)" ::: "memory");
      PH_SYNC();
      __builtin_amdgcn_s_setprio(1); MMA_QUAD(1, 0, bf_); __builtin_amdgcn_s_setprio(0);
      PH_SYNC();
      // ---- K-tile 2i+1 (buf1) ----
      LDA(0, 16384); LDB(0, 16384);
      stage_half(t2, 1);
      PH_SYNC();
      __builtin_amdgcn_s_setprio(1); MMA_QUAD(0, 0, bf_); __builtin_amdgcn_s_setprio(0);
      PH_SYNC();
      LDB(1, 16384);
      stage_half(t2, 2);
      PH_SYNC();
      __builtin_amdgcn_s_setprio(1); MMA_QUAD(0, 2, bf_ + 4); __builtin_amdgcn_s_setprio(0);
      PH_SYNC();
      LDA(1, 16384);
      stage_half(t2, 3);
      PH_SYNC();
      __builtin_amdgcn_s_setprio(1); MMA_QUAD(1, 2, bf_ + 4); __builtin_amdgcn_s_setprio(0);
      PH_SYNC();
      stage_half(t3, 0);
      if (!lastGate) asm volatile("s_waitcnt vmcnt(2)" ::: "memory");
      PH_SYNC();
      __builtin_amdgcn_s_setprio(1); MMA_QUAD(1, 0, bf_); __builtin_amdgcn_s_setprio(0);
      PH_SYNC();
    }

    // transition: pre-stage next-tau1's remaining halves BEFORE the stores
    stage_half(NT + 1, 1);
    stage_half(NT + 1, 2);
    stage_half(NT + 1, 3);
    asm volatile("" ::: "memory");   // pin epilogue mem-ops after the stages

    // epilogue (swapped D): row(M) = l&15, col(N) = (l>>4)*4 + q
    #pragma unroll
    for (int m = 0; m < 8; m++){
      int gr = bRow + wr * 128 + m * 16 + (l & 15);
      #pragma unroll
      for (int n = 0; n < 4; n++){
        int gc = bCol + wc * 64 + n * 16 + ((l >> 4) * 4);
        f32x4 v = acc[m][n] + bv4[n];
        *(f32x4*)(outf + (size_t)gr * N + gc) = v;
        acc[m][n] = (f32x4){0.f, 0.f, 0.f, 0.f};
      }
    }
    pre = true;
    bRow = nRow; bCol = nCol;
  }
}

// ============ 128x128 8-phase GEMM, BK=64, 8 waves, 2 blocks/CU ===============
#define MMA2(MH, NL) \
  { _Pragma("unroll") for (int mi = 0; mi < 2; mi++){ \
    _Pragma("unroll") for (int ks = 0; ks < 2; ks++){ \
      acc[(MH)*2+mi][(NL)] = __builtin_amdgcn_mfma_f32_16x16x32_bf16(bf_[(NL)*2+ks], af[mi*2+ks], acc[(MH)*2+mi][(NL)], 0, 0, 0); } } }

#define LDA2(MH, BO) \
  { _Pragma("unroll") for (int mi = 0; mi < 2; mi++){ \
    _Pragma("unroll") for (int ks = 0; ks < 2; ks++){ \
      af[mi*2+ks] = *(const s16x8*)(pa0 + (BO) + ((MH)*2+mi)*1024 + ((ks ^ kb) * 32)); } } }

#define LDB2(NL, BO) \
  { _Pragma("unroll") for (int ks = 0; ks < 2; ks++){ \
    bf_[(NL)*2+ks] = *(const s16x8*)(pb0 + (BO) + (NL)*1024 + ((ks ^ kb) * 32)); } }

template<int EPI>
__global__ __launch_bounds__(512, 4) void k_gemm8b(
    const u16* __restrict__ A, const u16* __restrict__ Bt,
    const float* __restrict__ bias, const float* __restrict__ aux,
    float* __restrict__ outf, u16* __restrict__ outbf,
    int N, int K, int tilesM, int tilesN){
  extern __shared__ u16 lds[];   // [A: 2buf x 8192][B at 16384: 2buf x 8192] u16
  const int t = threadIdx.x;
  const int w = t >> 6, l = t & 63;
  const int wr = w >> 2, wc = w & 3;     // 2M x 4N waves; wave out 64x32
  const int NT = K >> 6;
  const int NI = NT >> 1;

  int nwg = tilesM * tilesN;
  int id = blockIdx.x, id2;
  if ((nwg & 7) == 0){ int c = nwg >> 3; id2 = (id & 7) * c + (id >> 3); }
  else id2 = id;
  int per = tilesM << 3;
  int g = id2 / per, r = id2 % per;
  int bm = r % tilesM;
  int bn = (g << 3) + r / tilesM;
  const int bRow = bm * 128, bCol = bn * 128;

  const int r0 = t >> 3;
  const int scol = (((t & 7) ^ ((t >> 3) & 7)) * 8);

  auto stage_half = [&](int tau, int q){   // q: 0=A.h0 1=A.h1 2=B.h0 3=B.h1
    if (tau >= NT) return;
    int h = q & 1;
    bool isA = q < 2;
    const u16* gp = (isA ? A + (size_t)bRow * K : Bt + (size_t)bCol * K)
                 + (size_t)(h * 64 + r0) * K + (size_t)tau * 64 + scol;
    u16* d = lds + (isA ? 0 : 16384) + ((tau & 1) * 8192) + h * 4096 + t * 8;
    gload_lds16(gp, d);
  };

  const int cb = (((l >> 4) ^ (l & 3)) * 8);
  const int kb = (l >> 2) & 1;
  const u16* pa0 = lds + wr * 4096 + (l & 15) * 64 + cb;
  const u16* pb0 = lds + 16384 + (wc >> 1) * 4096 + ((wc & 1) * 32 + (l & 15)) * 64 + cb;

  f32x4 acc[4][2] = {};
  s16x8 af[4], bf_[4];

  stage_half(0, 0); stage_half(0, 1); stage_half(0, 2); stage_half(0, 3);
  stage_half(1, 0);
  asm volatile("s_waitcnt vmcnt(1)" ::: "memory");
  PH_SYNC();

  for (int i = 0; i < NI; i++){
    const int t1 = 2 * i + 1, t2 = 2 * i + 2, t3 = 2 * i + 3;
    const bool last = (i + 1 == NI);
    // ---- K-tile 2i (buf0) ----
    LDA2(0, 0); LDB2(0, 0);
    stage_half(t1, 1);
    PH_SYNC();
    __builtin_amdgcn_s_setprio(1); MMA2(0, 0); __builtin_amdgcn_s_setprio(0);
    PH_SYNC();
    LDB2(1, 0);
    stage_half(t1, 2);
    PH_SYNC();
    __builtin_amdgcn_s_setprio(1); MMA2(0, 1); __builtin_amdgcn_s_setprio(0);
    PH_SYNC();
    LDA2(1, 0);
    stage_half(t1, 3);
    PH_SYNC();
    __builtin_amdgcn_s_setprio(1); MMA2(1, 1); __builtin_amdgcn_s_setprio(0);
    PH_SYNC();
    stage_half(t2, 0);
    if (!last) asm volatile("s_waitcnt vmcnt(1)" ::: "memory");
    else       asm volatile("s_waitcnt vmcnt(0)" ::: "memory");
    PH_SYNC();
    __builtin_amdgcn_s_setprio(1); MMA2(1, 0); __builtin_amdgcn_s_setprio(0);
    PH_SYNC();
    // ---- K-tile 2i+1 (buf1) ----
    LDA2(0, 8192); LDB2(0, 8192);
    stage_half(t2, 1);
    PH_SYNC();
    __builtin_amdgcn_s_setprio(1); MMA2(0, 0); __builtin_amdgcn_s_setprio(0);
    PH_SYNC();
    LDB2(1, 8192);
    stage_half(t2, 2);
    PH_SYNC();
    __builtin_amdgcn_s_setprio(1); MMA2(0, 1); __builtin_amdgcn_s_setprio(0);
    PH_SYNC();
    LDA2(1, 8192);
    stage_half(t2, 3);
    PH_SYNC();
    __builtin_amdgcn_s_setprio(1); MMA2(1, 1); __builtin_amdgcn_s_setprio(0);
    PH_SYNC();
    stage_half(t3, 0);
    if (!last) asm volatile("s_waitcnt vmcnt(1)" ::: "memory");
    PH_SYNC();
    __builtin_amdgcn_s_setprio(1); MMA2(1, 0); __builtin_amdgcn_s_setprio(0);
    PH_SYNC();
  }

  // epilogue (swapped D): row(M) = l&15, col(N) = (l>>4)*4 + q
  #pragma unroll
  for (int m = 0; m < 4; m++){
    int gr = bRow + wr * 64 + m * 16 + (l & 15);
    #pragma unroll
    for (int n = 0; n < 2; n++){
      int gc = bCol + wc * 32 + n * 16 + ((l >> 4) * 4);
      size_t o = (size_t)gr * N + gc;
      f32x4 v = acc[m][n] + *(const f32x4*)(bias + gc);
      if constexpr (EPI == EP_GATE){
        f32x4 a = *(const f32x4*)(aux + o);
        u16x4 rr;
        #pragma unroll
        for (int q = 0; q < 4; q++) rr[q] = f2b(a[q] / (1.f + expf(-v[q])));
        *(u16x4*)(outbf + o) = rr;
      } else if constexpr (EPI == EP_TANH){
        u16x4 rr;
        #pragma unroll
        for (int q = 0; q < 4; q++) rr[q] = f2b(tanhf(v[q]));
        *(u16x4*)(outbf + o) = rr;
      } else if constexpr (EPI == EP_RESID){
        v += *(const f32x4*)(aux + o);
        *(f32x4*)(outf + o) = v;
        u16x4 rr;
        #pragma unroll
        for (int q = 0; q < 4; q++) rr[q] = f2b(v[q]);
        *(u16x4*)(outbf + o) = rr;
      } else if constexpr (EPI == EP_BIASF){
        *(f32x4*)(outf + o) = v;
      } else if constexpr (EPI == EP_AO){
        v += *(const f32x4*)(aux + o);
        *(f32x4*)(outf + o) = v;
      } else {
        *(f32x4*)(outf + o) = v;
      }
    }
  }
}

// -------- windowed attention: 4 tokens per block (1 wave each) ----------------
__global__ void k_attn(const float* __restrict__ qkv, u16* __restrict__ aob){
  int s = blockIdx.x * 4 + (threadIdx.x >> 6);
  int l = threadIdx.x & 63;
  const float* qp = qkv + (size_t)s * QKVN;
  float qr[4];
  #pragma unroll
  for (int r = 0; r < 4; r++) qr[r] = qp[l + 64 * r];
  float sc[9];
  float mx = -1e30f;
  #pragma unroll
  for (int j = 0; j <= 8; j++){
    int sj = s - j;
    bool ok = sj >= 0;
    int row = ok ? sj : 0;
    const float* kp = qkv + (size_t)row * QKVN + RDIM;
    float p = 0.f;
    #pragma unroll
    for (int r = 0; r < 4; r++) p += qr[r] * kp[l + 64 * r];
    #pragma unroll
    for (int off = 32; off; off >>= 1) p += __shfl_xor(p, off);
    p = ok ? p * 0.0625f : -1e30f;   // /sqrt(256)
    sc[j] = p;
    mx = fmaxf(mx, p);
  }
  float den = 0.f;
  #pragma unroll
  for (int j = 0; j <= 8; j++){ sc[j] = expf(sc[j] - mx); den += sc[j]; }
  float inv = 1.f / den;
  #pragma unroll
  for (int r = 0; r < 4; r++){
    float a = 0.f;
    #pragma unroll
    for (int j = 0; j <= 8; j++){
      int sj = s - j;
      int row = sj >= 0 ? sj : 0;
      a += sc[j] * qkv[(size_t)row * QKVN + 512 + l + 64 * r];
    }
    aob[(size_t)s * RDIM + l + 64 * r] = f2b(a * inv);
  }
}

// -------- chunk link ----------------------------------------------------------
__global__ void k_chunk(const float* __restrict__ xin, float* __restrict__ xout,
                        u16* __restrict__ xb){
  int s = blockIdx.x;
  int d = blockIdx.y * 256 + threadIdx.x;
  int ci = s >> 6;
  float v = xin[(size_t)s * DIM + d];
  float wsum = 1.f;
  if (ci > 0){ v += 0.5f * xin[(size_t)(s - 64) * DIM + d]; wsum += 0.5f; }
  if (ci < 63){ v += 0.5f * xin[(size_t)(s + 64) * DIM + d]; wsum += 0.5f; }
  v /= wsum;
  size_t o = (size_t)s * DIM + d;
  xout[o] = v; xb[o] = f2b(v);
}

extern "C" void kernel_launch(void* const* d_in, const int* in_sizes, int n_in,
                              void* d_out, int out_size, void* d_ws, size_t ws_size,
                              hipStream_t stream){
  const int*   idx  = (const int*)d_in[0];
  const float* emb  = (const float*)d_in[1];
  const float* pos  = (const float*)d_in[2];
  const float* Wg   = (const float*)d_in[3];
  const float* bg   = (const float*)d_in[4];
  const float* Ws_  = (const float*)d_in[5];
  const float* bs   = (const float*)d_in[6];
  const float* Wo   = (const float*)d_in[7];
  const float* bo   = (const float*)d_in[8];
  const float* Wq   = (const float*)d_in[9];
  const float* Wk   = (const float*)d_in[10];
  const float* Wv   = (const float*)d_in[11];
  const float* Wao  = (const float*)d_in[12];
  const float* bq   = (const float*)d_in[13];
  const float* bk   = (const float*)d_in[14];
  const float* bv   = (const float*)d_in[15];
  const float* bao  = (const float*)d_in[16];
  const float* outW = (const float*)d_in[17];
  const float* outb = (const float*)d_in[18];
  float* out = (float*)d_out;

  char* p = (char*)d_ws;
  auto alloc = [&](size_t n)->char*{ char* r = p; p += (n + 255) & ~(size_t)255; return r; };
  float* xfA  = (float*)alloc((size_t)S_LEN * DIM * 4);
  float* xfB  = (float*)alloc((size_t)S_LEN * DIM * 4);
  u16*   xb   = (u16*)  alloc((size_t)S_LEN * DIM * 2);
  u16*   xgb  = (u16*)  alloc((size_t)S_LEN * DIM * 2);
  u16*   tbuf = (u16*)  alloc((size_t)S_LEN * HID * 2);
  float* qkvf = (float*)alloc((size_t)S_LEN * QKVN * 4);
  u16*   aob  = (u16*)  alloc((size_t)S_LEN * RDIM * 2);
  float* bqkv2= (float*)alloc(2 * QKVN * 4);
  u16*   WgT  = (u16*)  alloc((size_t)NLAYER * DIM * DIM * 2);
  u16*   WsT  = (u16*)  alloc((size_t)NLAYER * DIM * HID * 2);
  u16*   WoT  = (u16*)  alloc((size_t)NLAYER * HID * DIM * 2);
  u16*   WqkvT= (u16*)  alloc((size_t)NLAYER * QKVN * DIM * 2);
  u16*   WaoT = (u16*)  alloc((size_t)NLAYER * RDIM * DIM * 2);
  u16*   outWT= (u16*)  alloc((size_t)VOCAB * DIM * 2);

  (void)hipFuncSetAttribute((const void*)&k_gemmL,
                      hipFuncAttributeMaxDynamicSharedMemorySize, 131072);
  (void)hipFuncSetAttribute((const void*)&k_gemm8b<EP_GATE>,
                      hipFuncAttributeMaxDynamicSharedMemorySize, 65536);
  (void)hipFuncSetAttribute((const void*)&k_gemm8b<EP_TANH>,
                      hipFuncAttributeMaxDynamicSharedMemorySize, 65536);
  (void)hipFuncSetAttribute((const void*)&k_gemm8b<EP_RESID>,
                      hipFuncAttributeMaxDynamicSharedMemorySize, 65536);
  (void)hipFuncSetAttribute((const void*)&k_gemm8b<EP_BIASF>,
                      hipFuncAttributeMaxDynamicSharedMemorySize, 65536);
  (void)hipFuncSetAttribute((const void*)&k_gemm8b<EP_AO>,
                      hipFuncAttributeMaxDynamicSharedMemorySize, 65536);

  // one prep launch: all transposes + qkv bias concats
  k_prep<<<13126, dim3(16, 16), 0, stream>>>(Wg, Ws_, Wo, Wq, Wk, Wv, Wao, outW,
                                             WgT, WsT, WoT, WqkvT, WaoT, outWT,
                                             bq, bk, bv, bqkv2);

  k_embed<<<dim3(S_LEN, DIM/256), 256, 0, stream>>>(idx, emb, pos, xfA, xb);

  float* curF = xfA; float* altF = xfB;
  for (int l = 0; l < NLAYER; l++){
    k_gemm8b<EP_GATE ><<<(S_LEN/128)*(DIM/128),  512, 65536, stream>>>(xb,  WgT  + (size_t)l*DIM*DIM,  bg + (size_t)l*DIM, curF, nullptr, xgb, DIM, DIM, S_LEN/128, DIM/128);
    k_gemm8b<EP_TANH ><<<(S_LEN/128)*(HID/128),  512, 65536, stream>>>(xgb, WsT  + (size_t)l*DIM*HID,  bs + (size_t)l*HID, nullptr, nullptr, tbuf, HID, DIM, S_LEN/128, HID/128);
    k_gemm8b<EP_RESID><<<(S_LEN/128)*(DIM/128),  512, 65536, stream>>>(tbuf,WoT  + (size_t)l*HID*DIM,  bo + (size_t)l*DIM, curF, curF, xb, DIM, HID, S_LEN/128, DIM/128);
    k_gemm8b<EP_BIASF><<<(S_LEN/128)*(QKVN/128), 512, 65536, stream>>>(xb,  WqkvT + (size_t)l*QKVN*DIM, bqkv2 + (size_t)l*QKVN, nullptr, qkvf, nullptr, QKVN, DIM, S_LEN/128, QKVN/128);
    k_attn<<<S_LEN/4, 256, 0, stream>>>(qkvf, aob);
    k_gemm8b<EP_AO   ><<<(S_LEN/128)*(DIM/128),  512, 65536, stream>>>(aob, WaoT + (size_t)l*RDIM*DIM, bao + (size_t)l*DIM, curF, curF, nullptr, DIM, RDIM, S_LEN/128, DIM/128);
    k_chunk<<<dim3(S_LEN, DIM/256), 256, 0, stream>>>(curF, altF, xb);
    float* tmp = curF; curF = altF; altF = tmp;
  }
  k_gemmL<<<256, 512, 131072, stream>>>(xb, outWT, outb, out, VOCAB, DIM, S_LEN/256, VOCAB/256);
}

// Round 13
// 822.641 us; speedup vs baseline: 1.0473x; 1.0210x over previous
//
#include <hip/hip_runtime.h>
#include <hip/hip_bf16.h>
#include <math.h>

#define S_LEN 4096
#define DIM   1024
#define HID   4096
#define NLAYER 2
#define RDIM  256
#define VOCAB 32000
#define QKVN  768

typedef unsigned short u16;
typedef __attribute__((ext_vector_type(8))) short s16x8;
typedef __attribute__((ext_vector_type(4))) float f32x4;
typedef __attribute__((ext_vector_type(4))) unsigned short u16x4;

__device__ inline u16 f2b(float f){
  unsigned u = __float_as_uint(f);
  u += 0x7fff + ((u >> 16) & 1);   // RNE
  return (u16)(u >> 16);
}

__device__ inline void gload_lds16(const void* g, void* l){
  __builtin_amdgcn_global_load_lds((__attribute__((address_space(1))) void*)(g),
                                   (__attribute__((address_space(3))) void*)(l), 16, 0, 0);
}

// ======== mega-prep: embed + all weight transposes + qkv bias concat =========
// ONE launch. blocks 0..16383: embed (s = id>>2, d-block = id&3)
//             16384..16389:    qkv bias concat
//             16390..29509:    64x64 transpose tiles (Wg|Ws|Wo|Wq|Wk|Wv|Wao|outW)
__global__ void k_prep(const float* __restrict__ Wg,  const float* __restrict__ Ws,
                       const float* __restrict__ Wo,  const float* __restrict__ Wq,
                       const float* __restrict__ Wk,  const float* __restrict__ Wv,
                       const float* __restrict__ Wao, const float* __restrict__ outW,
                       u16* __restrict__ WgT, u16* __restrict__ WsT, u16* __restrict__ WoT,
                       u16* __restrict__ WqkvT, u16* __restrict__ WaoT, u16* __restrict__ outWT,
                       const float* __restrict__ bq, const float* __restrict__ bk,
                       const float* __restrict__ bv, float* __restrict__ bqkv2,
                       const int* __restrict__ idx, const float* __restrict__ emb,
                       const float* __restrict__ pos, float* __restrict__ xf,
                       u16* __restrict__ xb){
  __shared__ float tile[64][65];
  int tx = threadIdx.x, ty = threadIdx.y;   // (16,16)
  int t = ty * 16 + tx;
  int id = blockIdx.x;
  if (id < 16384){   // embed
    int s = id >> 2;
    int d = (id & 3) * 256 + t;
    float v = emb[(size_t)idx[s] * DIM + d] + pos[(size_t)s * DIM + d];
    if (s > 0){
      float x0 = emb[(size_t)idx[0] * DIM + d] + pos[d];
      v += exp2f((float)s * -0.3219280948873623f) * x0;  // 0.8^s
    }
    size_t o = (size_t)s * DIM + d;
    xf[o] = v; xb[o] = f2b(v);
    return;
  }
  id -= 16384;
  if (id < 6){
    int l = id / 3, sel = id % 3;
    const float* s = sel == 0 ? bq : (sel == 1 ? bk : bv);
    bqkv2[l * 768 + sel * 256 + t] = s[(size_t)l * 256 + t];
    return;
  }
  id -= 6;
  const float* src; u16* dst; int K, N, bx, by;
  if (id < 512){
    int z = id >> 8, lo = id & 255;
    src = Wg + (size_t)z * DIM * DIM; dst = WgT + (size_t)z * DIM * DIM;
    K = DIM; N = DIM; bx = lo & 15; by = lo >> 4;
  } else if (id < 2560){
    int local = id - 512; int z = local >> 10, lo = local & 1023;
    src = Ws + (size_t)z * DIM * HID; dst = WsT + (size_t)z * DIM * HID;
    K = DIM; N = HID; bx = lo & 63; by = lo >> 6;
  } else if (id < 4608){
    int local = id - 2560; int z = local >> 10, lo = local & 1023;
    src = Wo + (size_t)z * HID * DIM; dst = WoT + (size_t)z * HID * DIM;
    K = HID; N = DIM; bx = lo & 15; by = lo >> 4;
  } else if (id < 4736){
    int local = id - 4608; int z = local >> 6, lo = local & 63;
    src = Wq + (size_t)z * DIM * RDIM; dst = WqkvT + (size_t)z * QKVN * DIM;
    K = DIM; N = RDIM; bx = lo & 3; by = lo >> 2;
  } else if (id < 4864){
    int local = id - 4736; int z = local >> 6, lo = local & 63;
    src = Wk + (size_t)z * DIM * RDIM; dst = WqkvT + (size_t)z * QKVN * DIM + (size_t)256 * DIM;
    K = DIM; N = RDIM; bx = lo & 3; by = lo >> 2;
  } else if (id < 4992){
    int local = id - 4864; int z = local >> 6, lo = local & 63;
    src = Wv + (size_t)z * DIM * RDIM; dst = WqkvT + (size_t)z * QKVN * DIM + (size_t)512 * DIM;
    K = DIM; N = RDIM; bx = lo & 3; by = lo >> 2;
  } else if (id < 5120){
    int local = id - 4992; int z = local >> 6, lo = local & 63;
    src = Wao + (size_t)z * RDIM * DIM; dst = WaoT + (size_t)z * RDIM * DIM;
    K = RDIM; N = DIM; bx = lo & 15; by = lo >> 4;
  } else {
    int local = id - 5120;
    src = outW; dst = outWT;
    K = DIM; N = VOCAB; bx = local % 500; by = local / 500;
  }
  int n0 = bx * 64, k0 = by * 64;
  #pragma unroll
  for (int i = 0; i < 4; i++){
    float4 v = *(const float4*)&src[(size_t)(k0 + ty + 16 * i) * N + n0 + tx * 4];
    tile[ty + 16 * i][tx * 4 + 0] = v.x;
    tile[ty + 16 * i][tx * 4 + 1] = v.y;
    tile[ty + 16 * i][tx * 4 + 2] = v.z;
    tile[ty + 16 * i][tx * 4 + 3] = v.w;
  }
  __syncthreads();
  #pragma unroll
  for (int i = 0; i < 4; i++){
    u16x4 o;
    #pragma unroll
    for (int j = 0; j < 4; j++) o[j] = f2b(tile[tx * 4 + j][ty + 16 * i]);
    *(u16x4*)&dst[(size_t)(n0 + ty + 16 * i) * K + k0 + tx * 4] = o;
  }
}

#define EP_GATE  0
#define EP_TANH  1
#define EP_RESID 2
#define EP_BIASF 3
#define EP_AO    4
#define EP_OUT   5

#define PH_SYNC() do{ asm volatile("" ::: "memory"); __builtin_amdgcn_s_barrier(); asm volatile("" ::: "memory"); }while(0)

// ============ 256x256 8-phase PERSISTENT GEMM (logits) — round-10 form ========
// Verified template (3-bit chunk-XOR swizzle both-sides, counted vmcnt(2),
// setprio, swapped-operand MFMA -> f32x4 stores) + persistence: grid=256,
// stride-256 tile walk; last iteration's t2/t3 stage slots ARE the next tile's
// prologue (tau >= NT maps to next-tile pointers; parity matches, NT even).

#define MMA_QUAD(MH, NLO, BF) \
  { _Pragma("unroll") for (int mi = 0; mi < 4; mi++){ \
    _Pragma("unroll") for (int ni = 0; ni < 2; ni++){ \
      _Pragma("unroll") for (int ks = 0; ks < 2; ks++){ \
        acc[(MH)*4+mi][(NLO)+ni] = __builtin_amdgcn_mfma_f32_16x16x32_bf16((BF)[ni*2+ks], af[mi*2+ks], acc[(MH)*4+mi][(NLO)+ni], 0, 0, 0); } } } }

#define LDA(MH, BO) \
  { _Pragma("unroll") for (int mi = 0; mi < 4; mi++){ \
    _Pragma("unroll") for (int ks = 0; ks < 2; ks++){ \
      af[mi*2+ks] = *(const s16x8*)(pa0 + (BO) + ((MH)*4+mi)*1024 + ((ks ^ kb) * 32)); } } }

#define LDB(NH, BO) \
  { _Pragma("unroll") for (int ni = 0; ni < 2; ni++){ \
    _Pragma("unroll") for (int ks = 0; ks < 2; ks++){ \
      bf_[(NH)*4+ni*2+ks] = *(const s16x8*)(pb0 + (BO) + ((NH)*2+ni)*1024 + ((ks ^ kb) * 32)); } } }

__global__ __launch_bounds__(512, 2) void k_gemmL(
    const u16* __restrict__ A, const u16* __restrict__ Bt,
    const float* __restrict__ bias, float* __restrict__ outf,
    int N, int K, int tilesM, int tilesN){
  extern __shared__ u16 lds[];   // [A: 2x16384][B at 32768: 2x16384] u16
  const int t = threadIdx.x;
  const int w = t >> 6, l = t & 63;
  const int wr = w >> 2, wc = w & 3;
  const int NT = K >> 6;
  const int NI = NT >> 1;
  const int nTiles = tilesM * tilesN;

  const int r0 = t >> 3;
  const int scol = (((t & 7) ^ ((t >> 3) & 7)) * 8);
  const int cb = (((l >> 4) ^ (l & 3)) * 8);
  const int kb = (l >> 2) & 1;
  const u16* pa0 = lds + (wr * 128 + (l & 15)) * 64 + cb;
  const u16* pb0 = lds + 32768 + (wc * 64 + (l & 15)) * 64 + cb;

  // 2-bm stripes, bn fastest within the stripe
  auto decode = [&](int idx2, int& bR, int& bC){
    int pr = tilesN * 2;
    int stripe = idx2 / pr, r2 = idx2 % pr;
    bR = (stripe * 2 + (r2 & 1)) * 256;
    bC = (r2 >> 1) * 256;
  };

  int tileIdx = blockIdx.x;
  if (tileIdx >= nTiles) return;
  int bRow, bCol, nRow = 0, nCol = 0;
  bool hasNext = false;
  decode(tileIdx, bRow, bCol);

  auto stage_half = [&](int tau, int q){                    // q: 0=A.h0 1=A.h1 2=B.h0 3=B.h1
    const u16* base;
    if (tau >= NT){
      if (!hasNext) return;
      tau -= NT;
      base = (q < 2) ? A + (size_t)nRow * K : Bt + (size_t)nCol * K;
    } else {
      base = (q < 2) ? A + (size_t)bRow * K : Bt + (size_t)bCol * K;
    }
    int h = q & 1;
    const u16* gp = base + (size_t)(h * 128 + r0) * K + (size_t)tau * 64 + scol;
    u16* d = lds + ((q < 2) ? 0 : 32768) + ((tau & 1) * 16384) + h * 8192 + t * 8;
    gload_lds16(gp, d);
    gload_lds16(gp + (size_t)64 * K, d + 4096);
  };

  f32x4 acc[8][4] = {};
  s16x8 af[8], bf_[8];

  // prologue (once): tile-0 complete + tile-1 half A0; leave 2 in flight
  stage_half(0, 0); stage_half(0, 1); stage_half(0, 2); stage_half(0, 3);
  stage_half(1, 0);
  asm volatile("s_waitcnt vmcnt(2)" ::: "memory");
  PH_SYNC();

  for (; tileIdx < nTiles; tileIdx += gridDim.x){
    int nIdx = tileIdx + gridDim.x;
    hasNext = nIdx < nTiles;
    if (hasNext) decode(nIdx, nRow, nCol);

    for (int i = 0; i < NI; i++){
      const int t1 = 2 * i + 1, t2 = 2 * i + 2, t3 = 2 * i + 3;
      const bool lastGate = (!hasNext) && (i + 1 == NI);
      // ---- K-tile 2i (buf0) ----
      LDA(0, 0); LDB(0, 0);
      stage_half(t1, 1);
      PH_SYNC();
      __builtin_amdgcn_s_setprio(1); MMA_QUAD(0, 0, bf_); __builtin_amdgcn_s_setprio(0);
      PH_SYNC();
      LDB(1, 0);
      stage_half(t1, 2);
      PH_SYNC();
      __builtin_amdgcn_s_setprio(1); MMA_QUAD(0, 2, bf_ + 4); __builtin_amdgcn_s_setprio(0);
      PH_SYNC();
      LDA(1, 0);
      stage_half(t1, 3);
      PH_SYNC();
      __builtin_amdgcn_s_setprio(1); MMA_QUAD(1, 2, bf_ + 4); __builtin_amdgcn_s_setprio(0);
      PH_SYNC();
      stage_half(t2, 0);
      if (!lastGate) asm volatile("s_waitcnt vmcnt(2)" ::: "memory");
      else           asm volatile("s_waitcnt vmcnt(0)" ::: "memory");
      PH_SYNC();
      __builtin_amdgcn_s_setprio(1); MMA_QUAD(1, 0, bf_); __builtin_amdgcn_s_setprio(0);
      PH_SYNC();
      // ---- K-tile 2i+1 (buf1) ----
      LDA(0, 16384); LDB(0, 16384);
      stage_half(t2, 1);
      PH_SYNC();
      __builtin_amdgcn_s_setprio(1); MMA_QUAD(0, 0, bf_); __builtin_amdgcn_s_setprio(0);
      PH_SYNC();
      LDB(1, 16384);
      stage_half(t2, 2);
      PH_SYNC();
      __builtin_amdgcn_s_setprio(1); MMA_QUAD(0, 2, bf_ + 4); __builtin_amdgcn_s_setprio(0);
      PH_SYNC();
      LDA(1, 16384);
      stage_half(t2, 3);
      PH_SYNC();
      __builtin_amdgcn_s_setprio(1); MMA_QUAD(1, 2, bf_ + 4); __builtin_amdgcn_s_setprio(0);
      PH_SYNC();
      stage_half(t3, 0);
      if (!lastGate) asm volatile("s_waitcnt vmcnt(2)" ::: "memory");
      PH_SYNC();
      __builtin_amdgcn_s_setprio(1); MMA_QUAD(1, 0, bf_); __builtin_amdgcn_s_setprio(0);
      PH_SYNC();
    }

    // epilogue (swapped D): row(M) = l&15, col(N) = (l>>4)*4 + q
    #pragma unroll
    for (int m = 0; m < 8; m++){
      int gr = bRow + wr * 128 + m * 16 + (l & 15);
      #pragma unroll
      for (int n = 0; n < 4; n++){
        int gc = bCol + wc * 64 + n * 16 + ((l >> 4) * 4);
        f32x4 v = acc[m][n] + *(const f32x4*)(bias + gc);
        *(f32x4*)(outf + (size_t)gr * N + gc) = v;
        acc[m][n] = (f32x4){0.f, 0.f, 0.f, 0.f};
      }
    }
    bRow = nRow; bCol = nCol;
  }
}

// ============ 128x128 8-phase GEMM, BK=64, 8 waves ============================
#define MMA2(MH, NL) \
  { _Pragma("unroll") for (int mi = 0; mi < 2; mi++){ \
    _Pragma("unroll") for (int ks = 0; ks < 2; ks++){ \
      acc[(MH)*2+mi][(NL)] = __builtin_amdgcn_mfma_f32_16x16x32_bf16(bf_[(NL)*2+ks], af[mi*2+ks], acc[(MH)*2+mi][(NL)], 0, 0, 0); } } }

#define LDA2(MH, BO) \
  { _Pragma("unroll") for (int mi = 0; mi < 2; mi++){ \
    _Pragma("unroll") for (int ks = 0; ks < 2; ks++){ \
      af[mi*2+ks] = *(const s16x8*)(pa0 + (BO) + ((MH)*2+mi)*1024 + ((ks ^ kb) * 32)); } } }

#define LDB2(NL, BO) \
  { _Pragma("unroll") for (int ks = 0; ks < 2; ks++){ \
    bf_[(NL)*2+ks] = *(const s16x8*)(pb0 + (BO) + (NL)*1024 + ((ks ^ kb) * 32)); } }

template<int EPI>
__global__ __launch_bounds__(512, 4) void k_gemm8b(
    const u16* __restrict__ A, const u16* __restrict__ Bt,
    const float* __restrict__ bias, const float* __restrict__ aux,
    float* __restrict__ outf, u16* __restrict__ outbf,
    int N, int K, int tilesM, int tilesN){
  extern __shared__ u16 lds[];   // [A: 2buf x 8192][B at 16384: 2buf x 8192] u16
  const int t = threadIdx.x;
  const int w = t >> 6, l = t & 63;
  const int wr = w >> 2, wc = w & 3;     // 2M x 4N waves; wave out 64x32
  const int NT = K >> 6;
  const int NI = NT >> 1;

  int nwg = tilesM * tilesN;
  int id = blockIdx.x, id2;
  if ((nwg & 7) == 0){ int c = nwg >> 3; id2 = (id & 7) * c + (id >> 3); }
  else id2 = id;
  int per = tilesM << 3;
  int g = id2 / per, r = id2 % per;
  int bm = r % tilesM;
  int bn = (g << 3) + r / tilesM;
  const int bRow = bm * 128, bCol = bn * 128;

  const int r0 = t >> 3;
  const int scol = (((t & 7) ^ ((t >> 3) & 7)) * 8);

  auto stage_half = [&](int tau, int q){   // q: 0=A.h0 1=A.h1 2=B.h0 3=B.h1
    if (tau >= NT) return;
    int h = q & 1;
    bool isA = q < 2;
    const u16* gp = (isA ? A + (size_t)bRow * K : Bt + (size_t)bCol * K)
                 + (size_t)(h * 64 + r0) * K + (size_t)tau * 64 + scol;
    u16* d = lds + (isA ? 0 : 16384) + ((tau & 1) * 8192) + h * 4096 + t * 8;
    gload_lds16(gp, d);
  };

  const int cb = (((l >> 4) ^ (l & 3)) * 8);
  const int kb = (l >> 2) & 1;
  const u16* pa0 = lds + wr * 4096 + (l & 15) * 64 + cb;
  const u16* pb0 = lds + 16384 + (wc >> 1) * 4096 + ((wc & 1) * 32 + (l & 15)) * 64 + cb;

  f32x4 acc[4][2] = {};
  s16x8 af[4], bf_[4];

  stage_half(0, 0); stage_half(0, 1); stage_half(0, 2); stage_half(0, 3);
  stage_half(1, 0);
  asm volatile("s_waitcnt vmcnt(1)" ::: "memory");
  PH_SYNC();

  for (int i = 0; i < NI; i++){
    const int t1 = 2 * i + 1, t2 = 2 * i + 2, t3 = 2 * i + 3;
    const bool last = (i + 1 == NI);
    // ---- K-tile 2i (buf0) ----
    LDA2(0, 0); LDB2(0, 0);
    stage_half(t1, 1);
    PH_SYNC();
    __builtin_amdgcn_s_setprio(1); MMA2(0, 0); __builtin_amdgcn_s_setprio(0);
    PH_SYNC();
    LDB2(1, 0);
    stage_half(t1, 2);
    PH_SYNC();
    __builtin_amdgcn_s_setprio(1); MMA2(0, 1); __builtin_amdgcn_s_setprio(0);
    PH_SYNC();
    LDA2(1, 0);
    stage_half(t1, 3);
    PH_SYNC();
    __builtin_amdgcn_s_setprio(1); MMA2(1, 1); __builtin_amdgcn_s_setprio(0);
    PH_SYNC();
    stage_half(t2, 0);
    if (!last) asm volatile("s_waitcnt vmcnt(1)" ::: "memory");
    else       asm volatile("s_waitcnt vmcnt(0)" ::: "memory");
    PH_SYNC();
    __builtin_amdgcn_s_setprio(1); MMA2(1, 0); __builtin_amdgcn_s_setprio(0);
    PH_SYNC();
    // ---- K-tile 2i+1 (buf1) ----
    LDA2(0, 8192); LDB2(0, 8192);
    stage_half(t2, 1);
    PH_SYNC();
    __builtin_amdgcn_s_setprio(1); MMA2(0, 0); __builtin_amdgcn_s_setprio(0);
    PH_SYNC();
    LDB2(1, 8192);
    stage_half(t2, 2);
    PH_SYNC();
    __builtin_amdgcn_s_setprio(1); MMA2(0, 1); __builtin_amdgcn_s_setprio(0);
    PH_SYNC();
    LDA2(1, 8192);
    stage_half(t2, 3);
    PH_SYNC();
    __builtin_amdgcn_s_setprio(1); MMA2(1, 1); __builtin_amdgcn_s_setprio(0);
    PH_SYNC();
    stage_half(t3, 0);
    if (!last) asm volatile("s_waitcnt vmcnt(1)" ::: "memory");
    PH_SYNC();
    __builtin_amdgcn_s_setprio(1); MMA2(1, 0); __builtin_amdgcn_s_setprio(0);
    PH_SYNC();
  }

  // epilogue (swapped D): row(M) = l&15, col(N) = (l>>4)*4 + q
  #pragma unroll
  for (int m = 0; m < 4; m++){
    int gr = bRow + wr * 64 + m * 16 + (l & 15);
    #pragma unroll
    for (int n = 0; n < 2; n++){
      int gc = bCol + wc * 32 + n * 16 + ((l >> 4) * 4);
      size_t o = (size_t)gr * N + gc;
      f32x4 v = acc[m][n] + *(const f32x4*)(bias + gc);
      if constexpr (EPI == EP_GATE){
        f32x4 a = *(const f32x4*)(aux + o);
        u16x4 rr;
        #pragma unroll
        for (int q = 0; q < 4; q++) rr[q] = f2b(a[q] / (1.f + expf(-v[q])));
        *(u16x4*)(outbf + o) = rr;
      } else if constexpr (EPI == EP_TANH){
        u16x4 rr;
        #pragma unroll
        for (int q = 0; q < 4; q++) rr[q] = f2b(tanhf(v[q]));
        *(u16x4*)(outbf + o) = rr;
      } else if constexpr (EPI == EP_RESID){
        v += *(const f32x4*)(aux + o);
        *(f32x4*)(outf + o) = v;
        u16x4 rr;
        #pragma unroll
        for (int q = 0; q < 4; q++) rr[q] = f2b(v[q]);
        *(u16x4*)(outbf + o) = rr;
      } else if constexpr (EPI == EP_BIASF){
        *(f32x4*)(outf + o) = v;
      } else if constexpr (EPI == EP_AO){
        v += *(const f32x4*)(aux + o);
        *(f32x4*)(outf + o) = v;
      } else {
        *(f32x4*)(outf + o) = v;
      }
    }
  }
}

// -------- windowed attention: 4 tokens per block (1 wave each) ----------------
__global__ void k_attn(const float* __restrict__ qkv, u16* __restrict__ aob){
  int s = blockIdx.x * 4 + (threadIdx.x >> 6);
  int l = threadIdx.x & 63;
  const float* qp = qkv + (size_t)s * QKVN;
  float qr[4];
  #pragma unroll
  for (int r = 0; r < 4; r++) qr[r] = qp[l + 64 * r];
  float sc[9];
  float mx = -1e30f;
  #pragma unroll
  for (int j = 0; j <= 8; j++){
    int sj = s - j;
    bool ok = sj >= 0;
    int row = ok ? sj : 0;
    const float* kp = qkv + (size_t)row * QKVN + RDIM;
    float p = 0.f;
    #pragma unroll
    for (int r = 0; r < 4; r++) p += qr[r] * kp[l + 64 * r];
    #pragma unroll
    for (int off = 32; off; off >>= 1) p += __shfl_xor(p, off);
    p = ok ? p * 0.0625f : -1e30f;   // /sqrt(256)
    sc[j] = p;
    mx = fmaxf(mx, p);
  }
  float den = 0.f;
  #pragma unroll
  for (int j = 0; j <= 8; j++){ sc[j] = expf(sc[j] - mx); den += sc[j]; }
  float inv = 1.f / den;
  #pragma unroll
  for (int r = 0; r < 4; r++){
    float a = 0.f;
    #pragma unroll
    for (int j = 0; j <= 8; j++){
      int sj = s - j;
      int row = sj >= 0 ? sj : 0;
      a += sc[j] * qkv[(size_t)row * QKVN + 512 + l + 64 * r];
    }
    aob[(size_t)s * RDIM + l + 64 * r] = f2b(a * inv);
  }
}

// -------- chunk link ----------------------------------------------------------
__global__ void k_chunk(const float* __restrict__ xin, float* __restrict__ xout,
                        u16* __restrict__ xb){
  int s = blockIdx.x;
  int d = blockIdx.y * 256 + threadIdx.x;
  int ci = s >> 6;
  float v = xin[(size_t)s * DIM + d];
  float wsum = 1.f;
  if (ci > 0){ v += 0.5f * xin[(size_t)(s - 64) * DIM + d]; wsum += 0.5f; }
  if (ci < 63){ v += 0.5f * xin[(size_t)(s + 64) * DIM + d]; wsum += 0.5f; }
  v /= wsum;
  size_t o = (size_t)s * DIM + d;
  xout[o] = v; xb[o] = f2b(v);
}

extern "C" void kernel_launch(void* const* d_in, const int* in_sizes, int n_in,
                              void* d_out, int out_size, void* d_ws, size_t ws_size,
                              hipStream_t stream){
  const int*   idx  = (const int*)d_in[0];
  const float* emb  = (const float*)d_in[1];
  const float* pos  = (const float*)d_in[2];
  const float* Wg   = (const float*)d_in[3];
  const float* bg   = (const float*)d_in[4];
  const float* Ws_  = (const float*)d_in[5];
  const float* bs   = (const float*)d_in[6];
  const float* Wo   = (const float*)d_in[7];
  const float* bo   = (const float*)d_in[8];
  const float* Wq   = (const float*)d_in[9];
  const float* Wk   = (const float*)d_in[10];
  const float* Wv   = (const float*)d_in[11];
  const float* Wao  = (const float*)d_in[12];
  const float* bq   = (const float*)d_in[13];
  const float* bk   = (const float*)d_in[14];
  const float* bv   = (const float*)d_in[15];
  const float* bao  = (const float*)d_in[16];
  const float* outW = (const float*)d_in[17];
  const float* outb = (const float*)d_in[18];
  float* out = (float*)d_out;

  char* p = (char*)d_ws;
  auto alloc = [&](size_t n)->char*{ char* r = p; p += (n + 255) & ~(size_t)255; return r; };
  float* xfA  = (float*)alloc((size_t)S_LEN * DIM * 4);
  float* xfB  = (float*)alloc((size_t)S_LEN * DIM * 4);
  u16*   xb   = (u16*)  alloc((size_t)S_LEN * DIM * 2);
  u16*   xgb  = (u16*)  alloc((size_t)S_LEN * DIM * 2);
  u16*   tbuf = (u16*)  alloc((size_t)S_LEN * HID * 2);
  float* qkvf = (float*)alloc((size_t)S_LEN * QKVN * 4);
  u16*   aob  = (u16*)  alloc((size_t)S_LEN * RDIM * 2);
  float* bqkv2= (float*)alloc(2 * QKVN * 4);
  u16*   WgT  = (u16*)  alloc((size_t)NLAYER * DIM * DIM * 2);
  u16*   WsT  = (u16*)  alloc((size_t)NLAYER * DIM * HID * 2);
  u16*   WoT  = (u16*)  alloc((size_t)NLAYER * HID * DIM * 2);
  u16*   WqkvT= (u16*)  alloc((size_t)NLAYER * QKVN * DIM * 2);
  u16*   WaoT = (u16*)  alloc((size_t)NLAYER * RDIM * DIM * 2);
  u16*   outWT= (u16*)  alloc((size_t)VOCAB * DIM * 2);

  (void)hipFuncSetAttribute((const void*)&k_gemmL,
                      hipFuncAttributeMaxDynamicSharedMemorySize, 131072);
  (void)hipFuncSetAttribute((const void*)&k_gemm8b<EP_GATE>,
                      hipFuncAttributeMaxDynamicSharedMemorySize, 65536);
  (void)hipFuncSetAttribute((const void*)&k_gemm8b<EP_TANH>,
                      hipFuncAttributeMaxDynamicSharedMemorySize, 65536);
  (void)hipFuncSetAttribute((const void*)&k_gemm8b<EP_RESID>,
                      hipFuncAttributeMaxDynamicSharedMemorySize, 65536);
  (void)hipFuncSetAttribute((const void*)&k_gemm8b<EP_BIASF>,
                      hipFuncAttributeMaxDynamicSharedMemorySize, 65536);
  (void)hipFuncSetAttribute((const void*)&k_gemm8b<EP_AO>,
                      hipFuncAttributeMaxDynamicSharedMemorySize, 65536);

  // one prep launch: embed + all transposes + qkv bias concats
  k_prep<<<29510, dim3(16, 16), 0, stream>>>(Wg, Ws_, Wo, Wq, Wk, Wv, Wao, outW,
                                             WgT, WsT, WoT, WqkvT, WaoT, outWT,
                                             bq, bk, bv, bqkv2,
                                             idx, emb, pos, xfA, xb);

  float* curF = xfA; float* altF = xfB;
  for (int l = 0; l < NLAYER; l++){
    k_gemm8b<EP_GATE ><<<(S_LEN/128)*(DIM/128),  512, 65536, stream>>>(xb,  WgT  + (size_t)l*DIM*DIM,  bg + (size_t)l*DIM, curF, nullptr, xgb, DIM, DIM, S_LEN/128, DIM/128);
    k_gemm8b<EP_TANH ><<<(S_LEN/128)*(HID/128),  512, 65536, stream>>>(xgb, WsT  + (size_t)l*DIM*HID,  bs + (size_t)l*HID, nullptr, nullptr, tbuf, HID, DIM, S_LEN/128, HID/128);
    k_gemm8b<EP_RESID><<<(S_LEN/128)*(DIM/128),  512, 65536, stream>>>(tbuf,WoT  + (size_t)l*HID*DIM,  bo + (size_t)l*DIM, curF, curF, xb, DIM, HID, S_LEN/128, DIM/128);
    k_gemm8b<EP_BIASF><<<(S_LEN/128)*(QKVN/128), 512, 65536, stream>>>(xb,  WqkvT + (size_t)l*QKVN*DIM, bqkv2 + (size_t)l*QKVN, nullptr, qkvf, nullptr, QKVN, DIM, S_LEN/128, QKVN/128);
    k_attn<<<S_LEN/4, 256, 0, stream>>>(qkvf, aob);
    k_gemm8b<EP_AO   ><<<(S_LEN/128)*(DIM/128),  512, 65536, stream>>>(aob, WaoT + (size_t)l*RDIM*DIM, bao + (size_t)l*DIM, curF, curF, nullptr, DIM, RDIM, S_LEN/128, DIM/128);
    k_chunk<<<dim3(S_LEN, DIM/256), 256, 0, stream>>>(curF, altF, xb);
    float* tmp = curF; curF = altF; altF = tmp;
  }
  k_gemmL<<<256, 512, 131072, stream>>>(xb, outWT, outb, out, VOCAB, DIM, S_LEN/256, VOCAB/256);
}

// Round 14
// 799.386 us; speedup vs baseline: 1.0777x; 1.0291x over previous
//
#include <hip/hip_runtime.h>
#include <hip/hip_bf16.h>
#include <math.h>

#define S_LEN 4096
#define DIM   1024
#define HID   4096
#define NLAYER 2
#define RDIM  256
#define VOCAB 32000
#define QKVN  768

typedef unsigned short u16;
typedef __attribute__((ext_vector_type(8))) short s16x8;
typedef __attribute__((ext_vector_type(4))) float f32x4;
typedef __attribute__((ext_vector_type(4))) unsigned short u16x4;

__device__ inline u16 f2b(float f){
  unsigned u = __float_as_uint(f);
  u += 0x7fff + ((u >> 16) & 1);   // RNE
  return (u16)(u >> 16);
}

__device__ inline void gload_lds16(const void* g, void* l){
  __builtin_amdgcn_global_load_lds((__attribute__((address_space(1))) void*)(g),
                                   (__attribute__((address_space(3))) void*)(l), 16, 0, 0);
}

// ======== mega-prep: embed + all weight transposes + qkv bias concat =========
__global__ void k_prep(const float* __restrict__ Wg,  const float* __restrict__ Ws,
                       const float* __restrict__ Wo,  const float* __restrict__ Wq,
                       const float* __restrict__ Wk,  const float* __restrict__ Wv,
                       const float* __restrict__ Wao, const float* __restrict__ outW,
                       u16* __restrict__ WgT, u16* __restrict__ WsT, u16* __restrict__ WoT,
                       u16* __restrict__ WqkvT, u16* __restrict__ WaoT, u16* __restrict__ outWT,
                       const float* __restrict__ bq, const float* __restrict__ bk,
                       const float* __restrict__ bv, float* __restrict__ bqkv2,
                       const int* __restrict__ idx, const float* __restrict__ emb,
                       const float* __restrict__ pos, float* __restrict__ xf,
                       u16* __restrict__ xb){
  __shared__ float tile[64][65];
  int tx = threadIdx.x, ty = threadIdx.y;   // (16,16)
  int t = ty * 16 + tx;
  int id = blockIdx.x;
  if (id < 16384){   // embed
    int s = id >> 2;
    int d = (id & 3) * 256 + t;
    float v = emb[(size_t)idx[s] * DIM + d] + pos[(size_t)s * DIM + d];
    if (s > 0){
      float x0 = emb[(size_t)idx[0] * DIM + d] + pos[d];
      v += exp2f((float)s * -0.3219280948873623f) * x0;  // 0.8^s
    }
    size_t o = (size_t)s * DIM + d;
    xf[o] = v; xb[o] = f2b(v);
    return;
  }
  id -= 16384;
  if (id < 6){
    int l = id / 3, sel = id % 3;
    const float* s = sel == 0 ? bq : (sel == 1 ? bk : bv);
    bqkv2[l * 768 + sel * 256 + t] = s[(size_t)l * 256 + t];
    return;
  }
  id -= 6;
  const float* src; u16* dst; int K, N, bx, by;
  if (id < 512){
    int z = id >> 8, lo = id & 255;
    src = Wg + (size_t)z * DIM * DIM; dst = WgT + (size_t)z * DIM * DIM;
    K = DIM; N = DIM; bx = lo & 15; by = lo >> 4;
  } else if (id < 2560){
    int local = id - 512; int z = local >> 10, lo = local & 1023;
    src = Ws + (size_t)z * DIM * HID; dst = WsT + (size_t)z * DIM * HID;
    K = DIM; N = HID; bx = lo & 63; by = lo >> 6;
  } else if (id < 4608){
    int local = id - 2560; int z = local >> 10, lo = local & 1023;
    src = Wo + (size_t)z * HID * DIM; dst = WoT + (size_t)z * HID * DIM;
    K = HID; N = DIM; bx = lo & 15; by = lo >> 4;
  } else if (id < 4736){
    int local = id - 4608; int z = local >> 6, lo = local & 63;
    src = Wq + (size_t)z * DIM * RDIM; dst = WqkvT + (size_t)z * QKVN * DIM;
    K = DIM; N = RDIM; bx = lo & 3; by = lo >> 2;
  } else if (id < 4864){
    int local = id - 4736; int z = local >> 6, lo = local & 63;
    src = Wk + (size_t)z * DIM * RDIM; dst = WqkvT + (size_t)z * QKVN * DIM + (size_t)256 * DIM;
    K = DIM; N = RDIM; bx = lo & 3; by = lo >> 2;
  } else if (id < 4992){
    int local = id - 4864; int z = local >> 6, lo = local & 63;
    src = Wv + (size_t)z * DIM * RDIM; dst = WqkvT + (size_t)z * QKVN * DIM + (size_t)512 * DIM;
    K = DIM; N = RDIM; bx = lo & 3; by = lo >> 2;
  } else if (id < 5120){
    int local = id - 4992; int z = local >> 6, lo = local & 63;
    src = Wao + (size_t)z * RDIM * DIM; dst = WaoT + (size_t)z * RDIM * DIM;
    K = RDIM; N = DIM; bx = lo & 15; by = lo >> 4;
  } else {
    int local = id - 5120;
    src = outW; dst = outWT;
    K = DIM; N = VOCAB; bx = local % 500; by = local / 500;
  }
  int n0 = bx * 64, k0 = by * 64;
  #pragma unroll
  for (int i = 0; i < 4; i++){
    float4 v = *(const float4*)&src[(size_t)(k0 + ty + 16 * i) * N + n0 + tx * 4];
    tile[ty + 16 * i][tx * 4 + 0] = v.x;
    tile[ty + 16 * i][tx * 4 + 1] = v.y;
    tile[ty + 16 * i][tx * 4 + 2] = v.z;
    tile[ty + 16 * i][tx * 4 + 3] = v.w;
  }
  __syncthreads();
  #pragma unroll
  for (int i = 0; i < 4; i++){
    u16x4 o;
    #pragma unroll
    for (int j = 0; j < 4; j++) o[j] = f2b(tile[tx * 4 + j][ty + 16 * i]);
    *(u16x4*)&dst[(size_t)(n0 + ty + 16 * i) * K + k0 + tx * 4] = o;
  }
}

#define EP_GATE  0
#define EP_TANH  1
#define EP_RESID 2
#define EP_BIASF 3
#define EP_AO    4
#define EP_OUT   5

#define PH_SYNC() do{ asm volatile("" ::: "memory"); __builtin_amdgcn_s_barrier(); asm volatile("" ::: "memory"); }while(0)

// ---- shared epilogue helper ------------------------------------------------
template<int EPI>
__device__ inline void epi_store(f32x4 v, size_t o, const float* aux,
                                 float* outf, u16* outbf){
  if constexpr (EPI == EP_GATE){
    f32x4 a = *(const f32x4*)(aux + o);
    u16x4 rr;
    #pragma unroll
    for (int q = 0; q < 4; q++) rr[q] = f2b(a[q] / (1.f + expf(-v[q])));
    *(u16x4*)(outbf + o) = rr;
  } else if constexpr (EPI == EP_TANH){
    u16x4 rr;
    #pragma unroll
    for (int q = 0; q < 4; q++) rr[q] = f2b(tanhf(v[q]));
    *(u16x4*)(outbf + o) = rr;
  } else if constexpr (EPI == EP_RESID){
    v += *(const f32x4*)(aux + o);
    *(f32x4*)(outf + o) = v;
    u16x4 rr;
    #pragma unroll
    for (int q = 0; q < 4; q++) rr[q] = f2b(v[q]);
    *(u16x4*)(outbf + o) = rr;
  } else if constexpr (EPI == EP_BIASF){
    *(f32x4*)(outf + o) = v;
  } else if constexpr (EPI == EP_AO){
    v += *(const f32x4*)(aux + o);
    *(f32x4*)(outf + o) = v;
  } else {
    *(f32x4*)(outf + o) = v;
  }
}

// ============ 256x256 8-phase PERSISTENT GEMM (logits) — round-10 form ========
#define MMA_QUAD(MH, NLO, BF) \
  { _Pragma("unroll") for (int mi = 0; mi < 4; mi++){ \
    _Pragma("unroll") for (int ni = 0; ni < 2; ni++){ \
      _Pragma("unroll") for (int ks = 0; ks < 2; ks++){ \
        acc[(MH)*4+mi][(NLO)+ni] = __builtin_amdgcn_mfma_f32_16x16x32_bf16((BF)[ni*2+ks], af[mi*2+ks], acc[(MH)*4+mi][(NLO)+ni], 0, 0, 0); } } } }

#define LDA(MH, BO) \
  { _Pragma("unroll") for (int mi = 0; mi < 4; mi++){ \
    _Pragma("unroll") for (int ks = 0; ks < 2; ks++){ \
      af[mi*2+ks] = *(const s16x8*)(pa0 + (BO) + ((MH)*4+mi)*1024 + ((ks ^ kb) * 32)); } } }

#define LDB(NH, BO) \
  { _Pragma("unroll") for (int ni = 0; ni < 2; ni++){ \
    _Pragma("unroll") for (int ks = 0; ks < 2; ks++){ \
      bf_[(NH)*4+ni*2+ks] = *(const s16x8*)(pb0 + (BO) + ((NH)*2+ni)*1024 + ((ks ^ kb) * 32)); } } }

__global__ __launch_bounds__(512, 2) void k_gemmL(
    const u16* __restrict__ A, const u16* __restrict__ Bt,
    const float* __restrict__ bias, float* __restrict__ outf,
    int N, int K, int tilesM, int tilesN){
  extern __shared__ u16 lds[];   // [A: 2x16384][B at 32768: 2x16384] u16
  const int t = threadIdx.x;
  const int w = t >> 6, l = t & 63;
  const int wr = w >> 2, wc = w & 3;
  const int NT = K >> 6;
  const int NI = NT >> 1;
  const int nTiles = tilesM * tilesN;

  const int r0 = t >> 3;
  const int scol = (((t & 7) ^ ((t >> 3) & 7)) * 8);
  const int cb = (((l >> 4) ^ (l & 3)) * 8);
  const int kb = (l >> 2) & 1;
  const u16* pa0 = lds + (wr * 128 + (l & 15)) * 64 + cb;
  const u16* pb0 = lds + 32768 + (wc * 64 + (l & 15)) * 64 + cb;

  auto decode = [&](int idx2, int& bR, int& bC){
    int pr = tilesN * 2;
    int stripe = idx2 / pr, r2 = idx2 % pr;
    bR = (stripe * 2 + (r2 & 1)) * 256;
    bC = (r2 >> 1) * 256;
  };

  int tileIdx = blockIdx.x;
  if (tileIdx >= nTiles) return;
  int bRow, bCol, nRow = 0, nCol = 0;
  bool hasNext = false;
  decode(tileIdx, bRow, bCol);

  auto stage_half = [&](int tau, int q){                    // q: 0=A.h0 1=A.h1 2=B.h0 3=B.h1
    const u16* base;
    if (tau >= NT){
      if (!hasNext) return;
      tau -= NT;
      base = (q < 2) ? A + (size_t)nRow * K : Bt + (size_t)nCol * K;
    } else {
      base = (q < 2) ? A + (size_t)bRow * K : Bt + (size_t)bCol * K;
    }
    int h = q & 1;
    const u16* gp = base + (size_t)(h * 128 + r0) * K + (size_t)tau * 64 + scol;
    u16* d = lds + ((q < 2) ? 0 : 32768) + ((tau & 1) * 16384) + h * 8192 + t * 8;
    gload_lds16(gp, d);
    gload_lds16(gp + (size_t)64 * K, d + 4096);
  };

  f32x4 acc[8][4] = {};
  s16x8 af[8], bf_[8];

  stage_half(0, 0); stage_half(0, 1); stage_half(0, 2); stage_half(0, 3);
  stage_half(1, 0);
  asm volatile("s_waitcnt vmcnt(2)" ::: "memory");
  PH_SYNC();

  for (; tileIdx < nTiles; tileIdx += gridDim.x){
    int nIdx = tileIdx + gridDim.x;
    hasNext = nIdx < nTiles;
    if (hasNext) decode(nIdx, nRow, nCol);

    for (int i = 0; i < NI; i++){
      const int t1 = 2 * i + 1, t2 = 2 * i + 2, t3 = 2 * i + 3;
      const bool lastGate = (!hasNext) && (i + 1 == NI);
      // ---- K-tile 2i (buf0) ----
      LDA(0, 0); LDB(0, 0);
      stage_half(t1, 1);
      PH_SYNC();
      __builtin_amdgcn_s_setprio(1); MMA_QUAD(0, 0, bf_); __builtin_amdgcn_s_setprio(0);
      PH_SYNC();
      LDB(1, 0);
      stage_half(t1, 2);
      PH_SYNC();
      __builtin_amdgcn_s_setprio(1); MMA_QUAD(0, 2, bf_ + 4); __builtin_amdgcn_s_setprio(0);
      PH_SYNC();
      LDA(1, 0);
      stage_half(t1, 3);
      PH_SYNC();
      __builtin_amdgcn_s_setprio(1); MMA_QUAD(1, 2, bf_ + 4); __builtin_amdgcn_s_setprio(0);
      PH_SYNC();
      stage_half(t2, 0);
      if (!lastGate) asm volatile("s_waitcnt vmcnt(2)" ::: "memory");
      else           asm volatile("s_waitcnt vmcnt(0)" ::: "memory");
      PH_SYNC();
      __builtin_amdgcn_s_setprio(1); MMA_QUAD(1, 0, bf_); __builtin_amdgcn_s_setprio(0);
      PH_SYNC();
      // ---- K-tile 2i+1 (buf1) ----
      LDA(0, 16384); LDB(0, 16384);
      stage_half(t2, 1);
      PH_SYNC();
      __builtin_amdgcn_s_setprio(1); MMA_QUAD(0, 0, bf_); __builtin_amdgcn_s_setprio(0);
      PH_SYNC();
      LDB(1, 16384);
      stage_half(t2, 2);
      PH_SYNC();
      __builtin_amdgcn_s_setprio(1); MMA_QUAD(0, 2, bf_ + 4); __builtin_amdgcn_s_setprio(0);
      PH_SYNC();
      LDA(1, 16384);
      stage_half(t2, 3);
      PH_SYNC();
      __builtin_amdgcn_s_setprio(1); MMA_QUAD(1, 2, bf_ + 4); __builtin_amdgcn_s_setprio(0);
      PH_SYNC();
      stage_half(t3, 0);
      if (!lastGate) asm volatile("s_waitcnt vmcnt(2)" ::: "memory");
      PH_SYNC();
      __builtin_amdgcn_s_setprio(1); MMA_QUAD(1, 0, bf_); __builtin_amdgcn_s_setprio(0);
      PH_SYNC();
    }

    #pragma unroll
    for (int m = 0; m < 8; m++){
      int gr = bRow + wr * 128 + m * 16 + (l & 15);
      #pragma unroll
      for (int n = 0; n < 4; n++){
        int gc = bCol + wc * 64 + n * 16 + ((l >> 4) * 4);
        f32x4 v = acc[m][n] + *(const f32x4*)(bias + gc);
        *(f32x4*)(outf + (size_t)gr * N + gc) = v;
        acc[m][n] = (f32x4){0.f, 0.f, 0.f, 0.f};
      }
    }
    bRow = nRow; bCol = nCol;
  }
}

// ============ 128x128 8-phase GEMM, BK=64, 8 waves (tanh / sculpt-up) =========
#define MMA2(MH, NL) \
  { _Pragma("unroll") for (int mi = 0; mi < 2; mi++){ \
    _Pragma("unroll") for (int ks = 0; ks < 2; ks++){ \
      acc[(MH)*2+mi][(NL)] = __builtin_amdgcn_mfma_f32_16x16x32_bf16(bf_[(NL)*2+ks], af[mi*2+ks], acc[(MH)*2+mi][(NL)], 0, 0, 0); } } }

#define LDA2(MH, BO) \
  { _Pragma("unroll") for (int mi = 0; mi < 2; mi++){ \
    _Pragma("unroll") for (int ks = 0; ks < 2; ks++){ \
      af[mi*2+ks] = *(const s16x8*)(pa0 + (BO) + ((MH)*2+mi)*1024 + ((ks ^ kb) * 32)); } } }

#define LDB2(NL, BO) \
  { _Pragma("unroll") for (int ks = 0; ks < 2; ks++){ \
    bf_[(NL)*2+ks] = *(const s16x8*)(pb0 + (BO) + (NL)*1024 + ((ks ^ kb) * 32)); } }

template<int EPI>
__global__ __launch_bounds__(512, 4) void k_gemm8b(
    const u16* __restrict__ A, const u16* __restrict__ Bt,
    const float* __restrict__ bias, const float* __restrict__ aux,
    float* __restrict__ outf, u16* __restrict__ outbf,
    int N, int K, int tilesM, int tilesN){
  extern __shared__ u16 lds[];   // [A: 2buf x 8192][B at 16384: 2buf x 8192] u16
  const int t = threadIdx.x;
  const int w = t >> 6, l = t & 63;
  const int wr = w >> 2, wc = w & 3;     // 2M x 4N waves; wave out 64x32
  const int NT = K >> 6;
  const int NI = NT >> 1;

  int nwg = tilesM * tilesN;
  int id = blockIdx.x, id2;
  if ((nwg & 7) == 0){ int c = nwg >> 3; id2 = (id & 7) * c + (id >> 3); }
  else id2 = id;
  int per = tilesM << 3;
  int g = id2 / per, r = id2 % per;
  int bm = r % tilesM;
  int bn = (g << 3) + r / tilesM;
  const int bRow = bm * 128, bCol = bn * 128;

  const int r0 = t >> 3;
  const int scol = (((t & 7) ^ ((t >> 3) & 7)) * 8);

  auto stage_half = [&](int tau, int q){   // q: 0=A.h0 1=A.h1 2=B.h0 3=B.h1
    if (tau >= NT) return;
    int h = q & 1;
    bool isA = q < 2;
    const u16* gp = (isA ? A + (size_t)bRow * K : Bt + (size_t)bCol * K)
                 + (size_t)(h * 64 + r0) * K + (size_t)tau * 64 + scol;
    u16* d = lds + (isA ? 0 : 16384) + ((tau & 1) * 8192) + h * 4096 + t * 8;
    gload_lds16(gp, d);
  };

  const int cb = (((l >> 4) ^ (l & 3)) * 8);
  const int kb = (l >> 2) & 1;
  const u16* pa0 = lds + wr * 4096 + (l & 15) * 64 + cb;
  const u16* pb0 = lds + 16384 + (wc >> 1) * 4096 + ((wc & 1) * 32 + (l & 15)) * 64 + cb;

  f32x4 acc[4][2] = {};
  s16x8 af[4], bf_[4];

  stage_half(0, 0); stage_half(0, 1); stage_half(0, 2); stage_half(0, 3);
  stage_half(1, 0);
  asm volatile("s_waitcnt vmcnt(1)" ::: "memory");
  PH_SYNC();

  for (int i = 0; i < NI; i++){
    const int t1 = 2 * i + 1, t2 = 2 * i + 2, t3 = 2 * i + 3;
    const bool last = (i + 1 == NI);
    // ---- K-tile 2i (buf0) ----
    LDA2(0, 0); LDB2(0, 0);
    stage_half(t1, 1);
    PH_SYNC();
    __builtin_amdgcn_s_setprio(1); MMA2(0, 0); __builtin_amdgcn_s_setprio(0);
    PH_SYNC();
    LDB2(1, 0);
    stage_half(t1, 2);
    PH_SYNC();
    __builtin_amdgcn_s_setprio(1); MMA2(0, 1); __builtin_amdgcn_s_setprio(0);
    PH_SYNC();
    LDA2(1, 0);
    stage_half(t1, 3);
    PH_SYNC();
    __builtin_amdgcn_s_setprio(1); MMA2(1, 1); __builtin_amdgcn_s_setprio(0);
    PH_SYNC();
    stage_half(t2, 0);
    if (!last) asm volatile("s_waitcnt vmcnt(1)" ::: "memory");
    else       asm volatile("s_waitcnt vmcnt(0)" ::: "memory");
    PH_SYNC();
    __builtin_amdgcn_s_setprio(1); MMA2(1, 0); __builtin_amdgcn_s_setprio(0);
    PH_SYNC();
    // ---- K-tile 2i+1 (buf1) ----
    LDA2(0, 8192); LDB2(0, 8192);
    stage_half(t2, 1);
    PH_SYNC();
    __builtin_amdgcn_s_setprio(1); MMA2(0, 0); __builtin_amdgcn_s_setprio(0);
    PH_SYNC();
    LDB2(1, 8192);
    stage_half(t2, 2);
    PH_SYNC();
    __builtin_amdgcn_s_setprio(1); MMA2(0, 1); __builtin_amdgcn_s_setprio(0);
    PH_SYNC();
    LDA2(1, 8192);
    stage_half(t2, 3);
    PH_SYNC();
    __builtin_amdgcn_s_setprio(1); MMA2(1, 1); __builtin_amdgcn_s_setprio(0);
    PH_SYNC();
    stage_half(t3, 0);
    if (!last) asm volatile("s_waitcnt vmcnt(1)" ::: "memory");
    PH_SYNC();
    __builtin_amdgcn_s_setprio(1); MMA2(1, 0); __builtin_amdgcn_s_setprio(0);
    PH_SYNC();
  }

  #pragma unroll
  for (int m = 0; m < 4; m++){
    int gr = bRow + wr * 64 + m * 16 + (l & 15);
    #pragma unroll
    for (int n = 0; n < 2; n++){
      int gc = bCol + wc * 32 + n * 16 + ((l >> 4) * 4);
      f32x4 v = acc[m][n] + *(const f32x4*)(bias + gc);
      epi_store<EPI>(v, (size_t)gr * N + gc, aux, outf, outbf);
    }
  }
}

// ===== 64x128 4-phase GEMM, BK=64, 8 waves, 48KB LDS -> 3 blocks/CU ==========
// For the block-starved layer GEMMs (gate/resid/qkv/ao: grids 512/512/384/512).
// Same verified swizzle + counted-gate discipline; A is ONE 64-row half, so the
// 8-phase skeleton collapses to 4 phases per 2 K-tiles with stage slots
// {p1: t1.A | p2: t1.B0,t1.B1,t2.A | p3: t2.B0 | p4: t2.B1,t3.A} and vmcnt(1)
// gates at p2/p4 (retire the previous tile's 3 stages, keep next A in flight).

#define MMA4(NL) \
  { _Pragma("unroll") for (int mi = 0; mi < 2; mi++){ \
    _Pragma("unroll") for (int ks = 0; ks < 2; ks++){ \
      acc[mi][(NL)] = __builtin_amdgcn_mfma_f32_16x16x32_bf16(bf_[(NL)*2+ks], af[mi*2+ks], acc[mi][(NL)], 0, 0, 0); } } }

#define LDA4(BO) \
  { _Pragma("unroll") for (int mi = 0; mi < 2; mi++){ \
    _Pragma("unroll") for (int ks = 0; ks < 2; ks++){ \
      af[mi*2+ks] = *(const s16x8*)(pa0 + (BO) + mi*1024 + ((ks ^ kb) * 32)); } } }

#define LDB4(NL, BO) \
  { _Pragma("unroll") for (int ks = 0; ks < 2; ks++){ \
    bf_[(NL)*2+ks] = *(const s16x8*)(pb0 + (BO) + (NL)*1024 + ((ks ^ kb) * 32)); } }

template<int EPI>
__global__ __launch_bounds__(512, 6) void k_gemm4(
    const u16* __restrict__ A, const u16* __restrict__ Bt,
    const float* __restrict__ bias, const float* __restrict__ aux,
    float* __restrict__ outf, u16* __restrict__ outbf,
    int N, int K, int tilesM, int tilesN){
  extern __shared__ u16 lds[];   // A: 2buf x 4096 u16; B at 8192: 2buf x 8192 u16
  const int t = threadIdx.x;
  const int w = t >> 6, l = t & 63;
  const int wr = w >> 2, wc = w & 3;   // 2M x 4N waves; wave out 32x32
  const int NT = K >> 6;
  const int NI = NT >> 1;

  int nwg = tilesM * tilesN;
  int id = blockIdx.x, id2;
  if ((nwg & 7) == 0){ int c = nwg >> 3; id2 = (id & 7) * c + (id >> 3); }
  else id2 = id;
  int per = tilesM << 3;
  int g = id2 / per, r = id2 % per;
  int bm = r % tilesM;
  int bn = (g << 3) + r / tilesM;
  const int bRow = bm * 64, bCol = bn * 128;

  const int r0 = t >> 3;
  const int scol = (((t & 7) ^ ((t >> 3) & 7)) * 8);

  auto stage = [&](int tau, int q){   // q: 0=A, 2=B.h0, 3=B.h1
    if (tau >= NT) return;
    bool isA = q == 0;
    int h = q & 1;
    const u16* gp = (isA ? A + (size_t)(bRow + r0) * K
                         : Bt + (size_t)(bCol + h * 64 + r0) * K)
                  + (size_t)tau * 64 + scol;
    u16* d = lds + (isA ? (tau & 1) * 4096
                        : 8192 + (tau & 1) * 8192 + h * 4096) + t * 8;
    gload_lds16(gp, d);
  };

  const int cb = (((l >> 4) ^ (l & 3)) * 8);
  const int kb = (l >> 2) & 1;
  const u16* pa0 = lds + (wr * 32 + (l & 15)) * 64 + cb;
  const u16* pb0 = lds + 8192 + (wc >> 1) * 4096 + ((wc & 1) * 32 + (l & 15)) * 64 + cb;

  f32x4 acc[2][2] = {};
  s16x8 af[4], bf_[4];

  // prologue: tile0 fully staged
  stage(0, 0); stage(0, 2); stage(0, 3);
  asm volatile("s_waitcnt vmcnt(0)" ::: "memory");
  PH_SYNC();

  for (int i = 0; i < NI; i++){
    const int t1 = 2 * i + 1, t2 = 2 * i + 2, t3 = 2 * i + 3;
    const bool last = (i + 1 == NI);
    // ---- K-tile 2i (buf0) ----
    // p1
    LDA4(0); LDB4(0, 0);
    stage(t1, 0);
    PH_SYNC();
    __builtin_amdgcn_s_setprio(1); MMA4(0); __builtin_amdgcn_s_setprio(0);
    PH_SYNC();
    // p2  (gate: t1 fully landed before p3 reads buf1)
    LDB4(1, 0);
    stage(t1, 2); stage(t1, 3); stage(t2, 0);
    if (!last) asm volatile("s_waitcnt vmcnt(1)" ::: "memory");
    else       asm volatile("s_waitcnt vmcnt(0)" ::: "memory");
    PH_SYNC();
    __builtin_amdgcn_s_setprio(1); MMA4(1); __builtin_amdgcn_s_setprio(0);
    PH_SYNC();
    // ---- K-tile 2i+1 (buf1) ----
    // p3
    LDA4(4096); LDB4(0, 8192);
    stage(t2, 2);
    PH_SYNC();
    __builtin_amdgcn_s_setprio(1); MMA4(0); __builtin_amdgcn_s_setprio(0);
    PH_SYNC();
    // p4  (gate: t2 fully landed before next p1 reads buf0)
    LDB4(1, 8192);
    stage(t2, 3); stage(t3, 0);
    if (!last) asm volatile("s_waitcnt vmcnt(1)" ::: "memory");
    PH_SYNC();
    __builtin_amdgcn_s_setprio(1); MMA4(1); __builtin_amdgcn_s_setprio(0);
    PH_SYNC();
  }

  // epilogue (swapped D): row(M) = l&15, col(N) = (l>>4)*4 + q
  #pragma unroll
  for (int m = 0; m < 2; m++){
    int gr = bRow + wr * 32 + m * 16 + (l & 15);
    #pragma unroll
    for (int n = 0; n < 2; n++){
      int gc = bCol + wc * 32 + n * 16 + ((l >> 4) * 4);
      f32x4 v = acc[m][n] + *(const f32x4*)(bias + gc);
      epi_store<EPI>(v, (size_t)gr * N + gc, aux, outf, outbf);
    }
  }
}

// -------- windowed attention: 4 tokens per block (1 wave each) ----------------
__global__ void k_attn(const float* __restrict__ qkv, u16* __restrict__ aob){
  int s = blockIdx.x * 4 + (threadIdx.x >> 6);
  int l = threadIdx.x & 63;
  const float* qp = qkv + (size_t)s * QKVN;
  float qr[4];
  #pragma unroll
  for (int r = 0; r < 4; r++) qr[r] = qp[l + 64 * r];
  float sc[9];
  float mx = -1e30f;
  #pragma unroll
  for (int j = 0; j <= 8; j++){
    int sj = s - j;
    bool ok = sj >= 0;
    int row = ok ? sj : 0;
    const float* kp = qkv + (size_t)row * QKVN + RDIM;
    float p = 0.f;
    #pragma unroll
    for (int r = 0; r < 4; r++) p += qr[r] * kp[l + 64 * r];
    #pragma unroll
    for (int off = 32; off; off >>= 1) p += __shfl_xor(p, off);
    p = ok ? p * 0.0625f : -1e30f;   // /sqrt(256)
    sc[j] = p;
    mx = fmaxf(mx, p);
  }
  float den = 0.f;
  #pragma unroll
  for (int j = 0; j <= 8; j++){ sc[j] = expf(sc[j] - mx); den += sc[j]; }
  float inv = 1.f / den;
  #pragma unroll
  for (int r = 0; r < 4; r++){
    float a = 0.f;
    #pragma unroll
    for (int j = 0; j <= 8; j++){
      int sj = s - j;
      int row = sj >= 0 ? sj : 0;
      a += sc[j] * qkv[(size_t)row * QKVN + 512 + l + 64 * r];
    }
    aob[(size_t)s * RDIM + l + 64 * r] = f2b(a * inv);
  }
}

// -------- chunk link ----------------------------------------------------------
__global__ void k_chunk(const float* __restrict__ xin, float* __restrict__ xout,
                        u16* __restrict__ xb){
  int s = blockIdx.x;
  int d = blockIdx.y * 256 + threadIdx.x;
  int ci = s >> 6;
  float v = xin[(size_t)s * DIM + d];
  float wsum = 1.f;
  if (ci > 0){ v += 0.5f * xin[(size_t)(s - 64) * DIM + d]; wsum += 0.5f; }
  if (ci < 63){ v += 0.5f * xin[(size_t)(s + 64) * DIM + d]; wsum += 0.5f; }
  v /= wsum;
  size_t o = (size_t)s * DIM + d;
  xout[o] = v; xb[o] = f2b(v);
}

extern "C" void kernel_launch(void* const* d_in, const int* in_sizes, int n_in,
                              void* d_out, int out_size, void* d_ws, size_t ws_size,
                              hipStream_t stream){
  const int*   idx  = (const int*)d_in[0];
  const float* emb  = (const float*)d_in[1];
  const float* pos  = (const float*)d_in[2];
  const float* Wg   = (const float*)d_in[3];
  const float* bg   = (const float*)d_in[4];
  const float* Ws_  = (const float*)d_in[5];
  const float* bs   = (const float*)d_in[6];
  const float* Wo   = (const float*)d_in[7];
  const float* bo   = (const float*)d_in[8];
  const float* Wq   = (const float*)d_in[9];
  const float* Wk   = (const float*)d_in[10];
  const float* Wv   = (const float*)d_in[11];
  const float* Wao  = (const float*)d_in[12];
  const float* bq   = (const float*)d_in[13];
  const float* bk   = (const float*)d_in[14];
  const float* bv   = (const float*)d_in[15];
  const float* bao  = (const float*)d_in[16];
  const float* outW = (const float*)d_in[17];
  const float* outb = (const float*)d_in[18];
  float* out = (float*)d_out;

  char* p = (char*)d_ws;
  auto alloc = [&](size_t n)->char*{ char* r = p; p += (n + 255) & ~(size_t)255; return r; };
  float* xfA  = (float*)alloc((size_t)S_LEN * DIM * 4);
  float* xfB  = (float*)alloc((size_t)S_LEN * DIM * 4);
  u16*   xb   = (u16*)  alloc((size_t)S_LEN * DIM * 2);
  u16*   xgb  = (u16*)  alloc((size_t)S_LEN * DIM * 2);
  u16*   tbuf = (u16*)  alloc((size_t)S_LEN * HID * 2);
  float* qkvf = (float*)alloc((size_t)S_LEN * QKVN * 4);
  u16*   aob  = (u16*)  alloc((size_t)S_LEN * RDIM * 2);
  float* bqkv2= (float*)alloc(2 * QKVN * 4);
  u16*   WgT  = (u16*)  alloc((size_t)NLAYER * DIM * DIM * 2);
  u16*   WsT  = (u16*)  alloc((size_t)NLAYER * DIM * HID * 2);
  u16*   WoT  = (u16*)  alloc((size_t)NLAYER * HID * DIM * 2);
  u16*   WqkvT= (u16*)  alloc((size_t)NLAYER * QKVN * DIM * 2);
  u16*   WaoT = (u16*)  alloc((size_t)NLAYER * RDIM * DIM * 2);
  u16*   outWT= (u16*)  alloc((size_t)VOCAB * DIM * 2);

  (void)hipFuncSetAttribute((const void*)&k_gemmL,
                      hipFuncAttributeMaxDynamicSharedMemorySize, 131072);
  (void)hipFuncSetAttribute((const void*)&k_gemm8b<EP_TANH>,
                      hipFuncAttributeMaxDynamicSharedMemorySize, 65536);
  (void)hipFuncSetAttribute((const void*)&k_gemm4<EP_GATE>,
                      hipFuncAttributeMaxDynamicSharedMemorySize, 49152);
  (void)hipFuncSetAttribute((const void*)&k_gemm4<EP_RESID>,
                      hipFuncAttributeMaxDynamicSharedMemorySize, 49152);
  (void)hipFuncSetAttribute((const void*)&k_gemm4<EP_BIASF>,
                      hipFuncAttributeMaxDynamicSharedMemorySize, 49152);
  (void)hipFuncSetAttribute((const void*)&k_gemm4<EP_AO>,
                      hipFuncAttributeMaxDynamicSharedMemorySize, 49152);

  // one prep launch: embed + all transposes + qkv bias concats
  k_prep<<<29510, dim3(16, 16), 0, stream>>>(Wg, Ws_, Wo, Wq, Wk, Wv, Wao, outW,
                                             WgT, WsT, WoT, WqkvT, WaoT, outWT,
                                             bq, bk, bv, bqkv2,
                                             idx, emb, pos, xfA, xb);

  float* curF = xfA; float* altF = xfB;
  for (int l = 0; l < NLAYER; l++){
    k_gemm4<EP_GATE ><<<(S_LEN/64)*(DIM/128),  512, 49152, stream>>>(xb,  WgT  + (size_t)l*DIM*DIM,  bg + (size_t)l*DIM, curF, nullptr, xgb, DIM, DIM, S_LEN/64, DIM/128);
    k_gemm8b<EP_TANH><<<(S_LEN/128)*(HID/128), 512, 65536, stream>>>(xgb, WsT  + (size_t)l*DIM*HID,  bs + (size_t)l*HID, nullptr, nullptr, tbuf, HID, DIM, S_LEN/128, HID/128);
    k_gemm4<EP_RESID><<<(S_LEN/64)*(DIM/128),  512, 49152, stream>>>(tbuf,WoT  + (size_t)l*HID*DIM,  bo + (size_t)l*DIM, curF, curF, xb, DIM, HID, S_LEN/64, DIM/128);
    k_gemm4<EP_BIASF><<<(S_LEN/64)*(QKVN/128), 512, 49152, stream>>>(xb,  WqkvT + (size_t)l*QKVN*DIM, bqkv2 + (size_t)l*QKVN, nullptr, qkvf, nullptr, QKVN, DIM, S_LEN/64, QKVN/128);
    k_attn<<<S_LEN/4, 256, 0, stream>>>(qkvf, aob);
    k_gemm4<EP_AO   ><<<(S_LEN/64)*(DIM/128),  512, 49152, stream>>>(aob, WaoT + (size_t)l*RDIM*DIM, bao + (size_t)l*DIM, curF, curF, nullptr, DIM, RDIM, S_LEN/64, DIM/128);
    k_chunk<<<dim3(S_LEN, DIM/256), 256, 0, stream>>>(curF, altF, xb);
    float* tmp = curF; curF = altF; altF = tmp;
  }
  k_gemmL<<<256, 512, 131072, stream>>>(xb, outWT, outb, out, VOCAB, DIM, S_LEN/256, VOCAB/256);
}

// Round 15
// 787.397 us; speedup vs baseline: 1.0941x; 1.0152x over previous
//
#include <hip/hip_runtime.h>
#include <hip/hip_bf16.h>
#include <math.h>

#define S_LEN 4096
#define DIM   1024
#define HID   4096
#define NLAYER 2
#define RDIM  256
#define VOCAB 32000
#define QKVN  768

typedef unsigned short u16;
typedef __attribute__((ext_vector_type(8))) short s16x8;
typedef __attribute__((ext_vector_type(4))) float f32x4;
typedef __attribute__((ext_vector_type(4))) unsigned short u16x4;

__device__ inline u16 f2b(float f){
  unsigned u = __float_as_uint(f);
  u += 0x7fff + ((u >> 16) & 1);   // RNE
  return (u16)(u >> 16);
}

__device__ inline void gload_lds16(const void* g, void* l){
  __builtin_amdgcn_global_load_lds((__attribute__((address_space(1))) void*)(g),
                                   (__attribute__((address_space(3))) void*)(l), 16, 0, 0);
}

// ======== mega-prep: embed + all weight transposes + qkv bias concat =========
__global__ void k_prep(const float* __restrict__ Wg,  const float* __restrict__ Ws,
                       const float* __restrict__ Wo,  const float* __restrict__ Wq,
                       const float* __restrict__ Wk,  const float* __restrict__ Wv,
                       const float* __restrict__ Wao, const float* __restrict__ outW,
                       u16* __restrict__ WgT, u16* __restrict__ WsT, u16* __restrict__ WoT,
                       u16* __restrict__ WqkvT, u16* __restrict__ WaoT, u16* __restrict__ outWT,
                       const float* __restrict__ bq, const float* __restrict__ bk,
                       const float* __restrict__ bv, float* __restrict__ bqkv2,
                       const int* __restrict__ idx, const float* __restrict__ emb,
                       const float* __restrict__ pos, float* __restrict__ xf,
                       u16* __restrict__ xb){
  __shared__ float tile[64][65];
  int tx = threadIdx.x, ty = threadIdx.y;   // (16,16)
  int t = ty * 16 + tx;
  int id = blockIdx.x;
  if (id < 16384){   // embed
    int s = id >> 2;
    int d = (id & 3) * 256 + t;
    float v = emb[(size_t)idx[s] * DIM + d] + pos[(size_t)s * DIM + d];
    if (s > 0){
      float x0 = emb[(size_t)idx[0] * DIM + d] + pos[d];
      v += exp2f((float)s * -0.3219280948873623f) * x0;  // 0.8^s
    }
    size_t o = (size_t)s * DIM + d;
    xf[o] = v; xb[o] = f2b(v);
    return;
  }
  id -= 16384;
  if (id < 6){
    int l = id / 3, sel = id % 3;
    const float* s = sel == 0 ? bq : (sel == 1 ? bk : bv);
    bqkv2[l * 768 + sel * 256 + t] = s[(size_t)l * 256 + t];
    return;
  }
  id -= 6;
  const float* src; u16* dst; int K, N, bx, by;
  if (id < 512){
    int z = id >> 8, lo = id & 255;
    src = Wg + (size_t)z * DIM * DIM; dst = WgT + (size_t)z * DIM * DIM;
    K = DIM; N = DIM; bx = lo & 15; by = lo >> 4;
  } else if (id < 2560){
    int local = id - 512; int z = local >> 10, lo = local & 1023;
    src = Ws + (size_t)z * DIM * HID; dst = WsT + (size_t)z * DIM * HID;
    K = DIM; N = HID; bx = lo & 63; by = lo >> 6;
  } else if (id < 4608){
    int local = id - 2560; int z = local >> 10, lo = local & 1023;
    src = Wo + (size_t)z * HID * DIM; dst = WoT + (size_t)z * HID * DIM;
    K = HID; N = DIM; bx = lo & 15; by = lo >> 4;
  } else if (id < 4736){
    int local = id - 4608; int z = local >> 6, lo = local & 63;
    src = Wq + (size_t)z * DIM * RDIM; dst = WqkvT + (size_t)z * QKVN * DIM;
    K = DIM; N = RDIM; bx = lo & 3; by = lo >> 2;
  } else if (id < 4864){
    int local = id - 4736; int z = local >> 6, lo = local & 63;
    src = Wk + (size_t)z * DIM * RDIM; dst = WqkvT + (size_t)z * QKVN * DIM + (size_t)256 * DIM;
    K = DIM; N = RDIM; bx = lo & 3; by = lo >> 2;
  } else if (id < 4992){
    int local = id - 4864; int z = local >> 6, lo = local & 63;
    src = Wv + (size_t)z * DIM * RDIM; dst = WqkvT + (size_t)z * QKVN * DIM + (size_t)512 * DIM;
    K = DIM; N = RDIM; bx = lo & 3; by = lo >> 2;
  } else if (id < 5120){
    int local = id - 4992; int z = local >> 6, lo = local & 63;
    src = Wao + (size_t)z * RDIM * DIM; dst = WaoT + (size_t)z * RDIM * DIM;
    K = RDIM; N = DIM; bx = lo & 15; by = lo >> 4;
  } else {
    int local = id - 5120;
    src = outW; dst = outWT;
    K = DIM; N = VOCAB; bx = local % 500; by = local / 500;
  }
  int n0 = bx * 64, k0 = by * 64;
  #pragma unroll
  for (int i = 0; i < 4; i++){
    float4 v = *(const float4*)&src[(size_t)(k0 + ty + 16 * i) * N + n0 + tx * 4];
    tile[ty + 16 * i][tx * 4 + 0] = v.x;
    tile[ty + 16 * i][tx * 4 + 1] = v.y;
    tile[ty + 16 * i][tx * 4 + 2] = v.z;
    tile[ty + 16 * i][tx * 4 + 3] = v.w;
  }
  __syncthreads();
  #pragma unroll
  for (int i = 0; i < 4; i++){
    u16x4 o;
    #pragma unroll
    for (int j = 0; j < 4; j++) o[j] = f2b(tile[tx * 4 + j][ty + 16 * i]);
    *(u16x4*)&dst[(size_t)(n0 + ty + 16 * i) * K + k0 + tx * 4] = o;
  }
}

#define EP_GATE  0
#define EP_TANH  1
#define EP_RESID 2
#define EP_BIASF 3
#define EP_AO    4
#define EP_OUT   5

#define PH_SYNC() do{ asm volatile("" ::: "memory"); __builtin_amdgcn_s_barrier(); asm volatile("" ::: "memory"); }while(0)

// ---- shared epilogue helper ------------------------------------------------
template<int EPI>
__device__ inline void epi_store(f32x4 v, size_t o, const float* aux,
                                 float* outf, u16* outbf){
  if constexpr (EPI == EP_GATE){
    f32x4 a = *(const f32x4*)(aux + o);
    u16x4 rr;
    #pragma unroll
    for (int q = 0; q < 4; q++) rr[q] = f2b(a[q] / (1.f + expf(-v[q])));
    *(u16x4*)(outbf + o) = rr;
  } else if constexpr (EPI == EP_TANH){
    u16x4 rr;
    #pragma unroll
    for (int q = 0; q < 4; q++) rr[q] = f2b(tanhf(v[q]));
    *(u16x4*)(outbf + o) = rr;
  } else if constexpr (EPI == EP_RESID){
    v += *(const f32x4*)(aux + o);
    *(f32x4*)(outf + o) = v;
    u16x4 rr;
    #pragma unroll
    for (int q = 0; q < 4; q++) rr[q] = f2b(v[q]);
    *(u16x4*)(outbf + o) = rr;
  } else if constexpr (EPI == EP_BIASF){
    *(f32x4*)(outf + o) = v;
  } else if constexpr (EPI == EP_AO){
    v += *(const f32x4*)(aux + o);
    *(f32x4*)(outf + o) = v;
  } else {
    *(f32x4*)(outf + o) = v;
  }
}

// ============ 256x256 8-phase PERSISTENT GEMM (logits) ========================
// Round-10 form + NON-TEMPORAL logit stores: the 512 MB write-once stream must
// not evict the B panels from L3 (write-eviction is the gate-latency source:
// FETCH 543 MB vs 72 MB unique operands at 1-phase gate slack).
#define MMA_QUAD(MH, NLO, BF) \
  { _Pragma("unroll") for (int mi = 0; mi < 4; mi++){ \
    _Pragma("unroll") for (int ni = 0; ni < 2; ni++){ \
      _Pragma("unroll") for (int ks = 0; ks < 2; ks++){ \
        acc[(MH)*4+mi][(NLO)+ni] = __builtin_amdgcn_mfma_f32_16x16x32_bf16((BF)[ni*2+ks], af[mi*2+ks], acc[(MH)*4+mi][(NLO)+ni], 0, 0, 0); } } } }

#define LDA(MH, BO) \
  { _Pragma("unroll") for (int mi = 0; mi < 4; mi++){ \
    _Pragma("unroll") for (int ks = 0; ks < 2; ks++){ \
      af[mi*2+ks] = *(const s16x8*)(pa0 + (BO) + ((MH)*4+mi)*1024 + ((ks ^ kb) * 32)); } } }

#define LDB(NH, BO) \
  { _Pragma("unroll") for (int ni = 0; ni < 2; ni++){ \
    _Pragma("unroll") for (int ks = 0; ks < 2; ks++){ \
      bf_[(NH)*4+ni*2+ks] = *(const s16x8*)(pb0 + (BO) + ((NH)*2+ni)*1024 + ((ks ^ kb) * 32)); } } }

__global__ __launch_bounds__(512, 2) void k_gemmL(
    const u16* __restrict__ A, const u16* __restrict__ Bt,
    const float* __restrict__ bias, float* __restrict__ outf,
    int N, int K, int tilesM, int tilesN){
  extern __shared__ u16 lds[];   // [A: 2x16384][B at 32768: 2x16384] u16
  const int t = threadIdx.x;
  const int w = t >> 6, l = t & 63;
  const int wr = w >> 2, wc = w & 3;
  const int NT = K >> 6;
  const int NI = NT >> 1;
  const int nTiles = tilesM * tilesN;

  const int r0 = t >> 3;
  const int scol = (((t & 7) ^ ((t >> 3) & 7)) * 8);
  const int cb = (((l >> 4) ^ (l & 3)) * 8);
  const int kb = (l >> 2) & 1;
  const u16* pa0 = lds + (wr * 128 + (l & 15)) * 64 + cb;
  const u16* pb0 = lds + 32768 + (wc * 64 + (l & 15)) * 64 + cb;

  auto decode = [&](int idx2, int& bR, int& bC){
    int pr = tilesN * 2;
    int stripe = idx2 / pr, r2 = idx2 % pr;
    bR = (stripe * 2 + (r2 & 1)) * 256;
    bC = (r2 >> 1) * 256;
  };

  int tileIdx = blockIdx.x;
  if (tileIdx >= nTiles) return;
  int bRow, bCol, nRow = 0, nCol = 0;
  bool hasNext = false;
  decode(tileIdx, bRow, bCol);

  auto stage_half = [&](int tau, int q){                    // q: 0=A.h0 1=A.h1 2=B.h0 3=B.h1
    const u16* base;
    if (tau >= NT){
      if (!hasNext) return;
      tau -= NT;
      base = (q < 2) ? A + (size_t)nRow * K : Bt + (size_t)nCol * K;
    } else {
      base = (q < 2) ? A + (size_t)bRow * K : Bt + (size_t)bCol * K;
    }
    int h = q & 1;
    const u16* gp = base + (size_t)(h * 128 + r0) * K + (size_t)tau * 64 + scol;
    u16* d = lds + ((q < 2) ? 0 : 32768) + ((tau & 1) * 16384) + h * 8192 + t * 8;
    gload_lds16(gp, d);
    gload_lds16(gp + (size_t)64 * K, d + 4096);
  };

  f32x4 acc[8][4] = {};
  s16x8 af[8], bf_[8];

  stage_half(0, 0); stage_half(0, 1); stage_half(0, 2); stage_half(0, 3);
  stage_half(1, 0);
  asm volatile("s_waitcnt vmcnt(2)" ::: "memory");
  PH_SYNC();

  for (; tileIdx < nTiles; tileIdx += gridDim.x){
    int nIdx = tileIdx + gridDim.x;
    hasNext = nIdx < nTiles;
    if (hasNext) decode(nIdx, nRow, nCol);

    for (int i = 0; i < NI; i++){
      const int t1 = 2 * i + 1, t2 = 2 * i + 2, t3 = 2 * i + 3;
      const bool lastGate = (!hasNext) && (i + 1 == NI);
      // ---- K-tile 2i (buf0) ----
      LDA(0, 0); LDB(0, 0);
      stage_half(t1, 1);
      PH_SYNC();
      __builtin_amdgcn_s_setprio(1); MMA_QUAD(0, 0, bf_); __builtin_amdgcn_s_setprio(0);
      PH_SYNC();
      LDB(1, 0);
      stage_half(t1, 2);
      PH_SYNC();
      __builtin_amdgcn_s_setprio(1); MMA_QUAD(0, 2, bf_ + 4); __builtin_amdgcn_s_setprio(0);
      PH_SYNC();
      LDA(1, 0);
      stage_half(t1, 3);
      PH_SYNC();
      __builtin_amdgcn_s_setprio(1); MMA_QUAD(1, 2, bf_ + 4); __builtin_amdgcn_s_setprio(0);
      PH_SYNC();
      stage_half(t2, 0);
      if (!lastGate) asm volatile("s_waitcnt vmcnt(2)" ::: "memory");
      else           asm volatile("s_waitcnt vmcnt(0)" ::: "memory");
      PH_SYNC();
      __builtin_amdgcn_s_setprio(1); MMA_QUAD(1, 0, bf_); __builtin_amdgcn_s_setprio(0);
      PH_SYNC();
      // ---- K-tile 2i+1 (buf1) ----
      LDA(0, 16384); LDB(0, 16384);
      stage_half(t2, 1);
      PH_SYNC();
      __builtin_amdgcn_s_setprio(1); MMA_QUAD(0, 0, bf_); __builtin_amdgcn_s_setprio(0);
      PH_SYNC();
      LDB(1, 16384);
      stage_half(t2, 2);
      PH_SYNC();
      __builtin_amdgcn_s_setprio(1); MMA_QUAD(0, 2, bf_ + 4); __builtin_amdgcn_s_setprio(0);
      PH_SYNC();
      LDA(1, 16384);
      stage_half(t2, 3);
      PH_SYNC();
      __builtin_amdgcn_s_setprio(1); MMA_QUAD(1, 2, bf_ + 4); __builtin_amdgcn_s_setprio(0);
      PH_SYNC();
      stage_half(t3, 0);
      if (!lastGate) asm volatile("s_waitcnt vmcnt(2)" ::: "memory");
      PH_SYNC();
      __builtin_amdgcn_s_setprio(1); MMA_QUAD(1, 0, bf_); __builtin_amdgcn_s_setprio(0);
      PH_SYNC();
    }

    #pragma unroll
    for (int m = 0; m < 8; m++){
      int gr = bRow + wr * 128 + m * 16 + (l & 15);
      #pragma unroll
      for (int n = 0; n < 4; n++){
        int gc = bCol + wc * 64 + n * 16 + ((l >> 4) * 4);
        f32x4 v = acc[m][n] + *(const f32x4*)(bias + gc);
        __builtin_nontemporal_store(v, (f32x4*)(outf + (size_t)gr * N + gc));
        acc[m][n] = (f32x4){0.f, 0.f, 0.f, 0.f};
      }
    }
    bRow = nRow; bCol = nCol;
  }
}

// ============ 128x128 8-phase GEMM, BK=64, 8 waves (tanh / sculpt-up) =========
#define MMA2(MH, NL) \
  { _Pragma("unroll") for (int mi = 0; mi < 2; mi++){ \
    _Pragma("unroll") for (int ks = 0; ks < 2; ks++){ \
      acc[(MH)*2+mi][(NL)] = __builtin_amdgcn_mfma_f32_16x16x32_bf16(bf_[(NL)*2+ks], af[mi*2+ks], acc[(MH)*2+mi][(NL)], 0, 0, 0); } } }

#define LDA2(MH, BO) \
  { _Pragma("unroll") for (int mi = 0; mi < 2; mi++){ \
    _Pragma("unroll") for (int ks = 0; ks < 2; ks++){ \
      af[mi*2+ks] = *(const s16x8*)(pa0 + (BO) + ((MH)*2+mi)*1024 + ((ks ^ kb) * 32)); } } }

#define LDB2(NL, BO) \
  { _Pragma("unroll") for (int ks = 0; ks < 2; ks++){ \
    bf_[(NL)*2+ks] = *(const s16x8*)(pb0 + (BO) + (NL)*1024 + ((ks ^ kb) * 32)); } }

template<int EPI>
__global__ __launch_bounds__(512, 4) void k_gemm8b(
    const u16* __restrict__ A, const u16* __restrict__ Bt,
    const float* __restrict__ bias, const float* __restrict__ aux,
    float* __restrict__ outf, u16* __restrict__ outbf,
    int N, int K, int tilesM, int tilesN){
  extern __shared__ u16 lds[];   // [A: 2buf x 8192][B at 16384: 2buf x 8192] u16
  const int t = threadIdx.x;
  const int w = t >> 6, l = t & 63;
  const int wr = w >> 2, wc = w & 3;     // 2M x 4N waves; wave out 64x32
  const int NT = K >> 6;
  const int NI = NT >> 1;

  int nwg = tilesM * tilesN;
  int id = blockIdx.x, id2;
  if ((nwg & 7) == 0){ int c = nwg >> 3; id2 = (id & 7) * c + (id >> 3); }
  else id2 = id;
  int per = tilesM << 3;
  int g = id2 / per, r = id2 % per;
  int bm = r % tilesM;
  int bn = (g << 3) + r / tilesM;
  const int bRow = bm * 128, bCol = bn * 128;

  const int r0 = t >> 3;
  const int scol = (((t & 7) ^ ((t >> 3) & 7)) * 8);

  auto stage_half = [&](int tau, int q){   // q: 0=A.h0 1=A.h1 2=B.h0 3=B.h1
    if (tau >= NT) return;
    int h = q & 1;
    bool isA = q < 2;
    const u16* gp = (isA ? A + (size_t)bRow * K : Bt + (size_t)bCol * K)
                 + (size_t)(h * 64 + r0) * K + (size_t)tau * 64 + scol;
    u16* d = lds + (isA ? 0 : 16384) + ((tau & 1) * 8192) + h * 4096 + t * 8;
    gload_lds16(gp, d);
  };

  const int cb = (((l >> 4) ^ (l & 3)) * 8);
  const int kb = (l >> 2) & 1;
  const u16* pa0 = lds + wr * 4096 + (l & 15) * 64 + cb;
  const u16* pb0 = lds + 16384 + (wc >> 1) * 4096 + ((wc & 1) * 32 + (l & 15)) * 64 + cb;

  f32x4 acc[4][2] = {};
  s16x8 af[4], bf_[4];

  stage_half(0, 0); stage_half(0, 1); stage_half(0, 2); stage_half(0, 3);
  stage_half(1, 0);
  asm volatile("s_waitcnt vmcnt(1)" ::: "memory");
  PH_SYNC();

  for (int i = 0; i < NI; i++){
    const int t1 = 2 * i + 1, t2 = 2 * i + 2, t3 = 2 * i + 3;
    const bool last = (i + 1 == NI);
    // ---- K-tile 2i (buf0) ----
    LDA2(0, 0); LDB2(0, 0);
    stage_half(t1, 1);
    PH_SYNC();
    __builtin_amdgcn_s_setprio(1); MMA2(0, 0); __builtin_amdgcn_s_setprio(0);
    PH_SYNC();
    LDB2(1, 0);
    stage_half(t1, 2);
    PH_SYNC();
    __builtin_amdgcn_s_setprio(1); MMA2(0, 1); __builtin_amdgcn_s_setprio(0);
    PH_SYNC();
    LDA2(1, 0);
    stage_half(t1, 3);
    PH_SYNC();
    __builtin_amdgcn_s_setprio(1); MMA2(1, 1); __builtin_amdgcn_s_setprio(0);
    PH_SYNC();
    stage_half(t2, 0);
    if (!last) asm volatile("s_waitcnt vmcnt(1)" ::: "memory");
    else       asm volatile("s_waitcnt vmcnt(0)" ::: "memory");
    PH_SYNC();
    __builtin_amdgcn_s_setprio(1); MMA2(1, 0); __builtin_amdgcn_s_setprio(0);
    PH_SYNC();
    // ---- K-tile 2i+1 (buf1) ----
    LDA2(0, 8192); LDB2(0, 8192);
    stage_half(t2, 1);
    PH_SYNC();
    __builtin_amdgcn_s_setprio(1); MMA2(0, 0); __builtin_amdgcn_s_setprio(0);
    PH_SYNC();
    LDB2(1, 8192);
    stage_half(t2, 2);
    PH_SYNC();
    __builtin_amdgcn_s_setprio(1); MMA2(0, 1); __builtin_amdgcn_s_setprio(0);
    PH_SYNC();
    LDA2(1, 8192);
    stage_half(t2, 3);
    PH_SYNC();
    __builtin_amdgcn_s_setprio(1); MMA2(1, 1); __builtin_amdgcn_s_setprio(0);
    PH_SYNC();
    stage_half(t3, 0);
    if (!last) asm volatile("s_waitcnt vmcnt(1)" ::: "memory");
    PH_SYNC();
    __builtin_amdgcn_s_setprio(1); MMA2(1, 0); __builtin_amdgcn_s_setprio(0);
    PH_SYNC();
  }

  #pragma unroll
  for (int m = 0; m < 4; m++){
    int gr = bRow + wr * 64 + m * 16 + (l & 15);
    #pragma unroll
    for (int n = 0; n < 2; n++){
      int gc = bCol + wc * 32 + n * 16 + ((l >> 4) * 4);
      f32x4 v = acc[m][n] + *(const f32x4*)(bias + gc);
      epi_store<EPI>(v, (size_t)gr * N + gc, aux, outf, outbf);
    }
  }
}

// ===== 64x128 4-phase GEMM, BK=64, 8 waves, 48KB LDS -> 3 blocks/CU ==========
#define MMA4(NL) \
  { _Pragma("unroll") for (int mi = 0; mi < 2; mi++){ \
    _Pragma("unroll") for (int ks = 0; ks < 2; ks++){ \
      acc[mi][(NL)] = __builtin_amdgcn_mfma_f32_16x16x32_bf16(bf_[(NL)*2+ks], af[mi*2+ks], acc[mi][(NL)], 0, 0, 0); } } }

#define LDA4(BO) \
  { _Pragma("unroll") for (int mi = 0; mi < 2; mi++){ \
    _Pragma("unroll") for (int ks = 0; ks < 2; ks++){ \
      af[mi*2+ks] = *(const s16x8*)(pa0 + (BO) + mi*1024 + ((ks ^ kb) * 32)); } } }

#define LDB4(NL, BO) \
  { _Pragma("unroll") for (int ks = 0; ks < 2; ks++){ \
    bf_[(NL)*2+ks] = *(const s16x8*)(pb0 + (BO) + (NL)*1024 + ((ks ^ kb) * 32)); } }

template<int EPI>
__global__ __launch_bounds__(512, 6) void k_gemm4(
    const u16* __restrict__ A, const u16* __restrict__ Bt,
    const float* __restrict__ bias, const float* __restrict__ aux,
    float* __restrict__ outf, u16* __restrict__ outbf,
    int N, int K, int tilesM, int tilesN){
  extern __shared__ u16 lds[];   // A: 2buf x 4096 u16; B at 8192: 2buf x 8192 u16
  const int t = threadIdx.x;
  const int w = t >> 6, l = t & 63;
  const int wr = w >> 2, wc = w & 3;   // 2M x 4N waves; wave out 32x32
  const int NT = K >> 6;
  const int NI = NT >> 1;

  int nwg = tilesM * tilesN;
  int id = blockIdx.x, id2;
  if ((nwg & 7) == 0){ int c = nwg >> 3; id2 = (id & 7) * c + (id >> 3); }
  else id2 = id;
  int per = tilesM << 3;
  int g = id2 / per, r = id2 % per;
  int bm = r % tilesM;
  int bn = (g << 3) + r / tilesM;
  const int bRow = bm * 64, bCol = bn * 128;

  const int r0 = t >> 3;
  const int scol = (((t & 7) ^ ((t >> 3) & 7)) * 8);

  auto stage = [&](int tau, int q){   // q: 0=A, 2=B.h0, 3=B.h1
    if (tau >= NT) return;
    bool isA = q == 0;
    int h = q & 1;
    const u16* gp = (isA ? A + (size_t)(bRow + r0) * K
                         : Bt + (size_t)(bCol + h * 64 + r0) * K)
                  + (size_t)tau * 64 + scol;
    u16* d = lds + (isA ? (tau & 1) * 4096
                        : 8192 + (tau & 1) * 8192 + h * 4096) + t * 8;
    gload_lds16(gp, d);
  };

  const int cb = (((l >> 4) ^ (l & 3)) * 8);
  const int kb = (l >> 2) & 1;
  const u16* pa0 = lds + (wr * 32 + (l & 15)) * 64 + cb;
  const u16* pb0 = lds + 8192 + (wc >> 1) * 4096 + ((wc & 1) * 32 + (l & 15)) * 64 + cb;

  f32x4 acc[2][2] = {};
  s16x8 af[4], bf_[4];

  stage(0, 0); stage(0, 2); stage(0, 3);
  asm volatile("s_waitcnt vmcnt(0)" ::: "memory");
  PH_SYNC();

  for (int i = 0; i < NI; i++){
    const int t1 = 2 * i + 1, t2 = 2 * i + 2, t3 = 2 * i + 3;
    const bool last = (i + 1 == NI);
    // ---- K-tile 2i (buf0) ----
    LDA4(0); LDB4(0, 0);
    stage(t1, 0);
    PH_SYNC();
    __builtin_amdgcn_s_setprio(1); MMA4(0); __builtin_amdgcn_s_setprio(0);
    PH_SYNC();
    LDB4(1, 0);
    stage(t1, 2); stage(t1, 3); stage(t2, 0);
    if (!last) asm volatile("s_waitcnt vmcnt(1)" ::: "memory");
    else       asm volatile("s_waitcnt vmcnt(0)" ::: "memory");
    PH_SYNC();
    __builtin_amdgcn_s_setprio(1); MMA4(1); __builtin_amdgcn_s_setprio(0);
    PH_SYNC();
    // ---- K-tile 2i+1 (buf1) ----
    LDA4(4096); LDB4(0, 8192);
    stage(t2, 2);
    PH_SYNC();
    __builtin_amdgcn_s_setprio(1); MMA4(0); __builtin_amdgcn_s_setprio(0);
    PH_SYNC();
    LDB4(1, 8192);
    stage(t2, 3); stage(t3, 0);
    if (!last) asm volatile("s_waitcnt vmcnt(1)" ::: "memory");
    PH_SYNC();
    __builtin_amdgcn_s_setprio(1); MMA4(1); __builtin_amdgcn_s_setprio(0);
    PH_SYNC();
  }

  #pragma unroll
  for (int m = 0; m < 2; m++){
    int gr = bRow + wr * 32 + m * 16 + (l & 15);
    #pragma unroll
    for (int n = 0; n < 2; n++){
      int gc = bCol + wc * 32 + n * 16 + ((l >> 4) * 4);
      f32x4 v = acc[m][n] + *(const f32x4*)(bias + gc);
      epi_store<EPI>(v, (size_t)gr * N + gc, aux, outf, outbf);
    }
  }
}

// -------- windowed attention: 4 tokens per block (1 wave each) ----------------
__global__ void k_attn(const float* __restrict__ qkv, u16* __restrict__ aob){
  int s = blockIdx.x * 4 + (threadIdx.x >> 6);
  int l = threadIdx.x & 63;
  const float* qp = qkv + (size_t)s * QKVN;
  float qr[4];
  #pragma unroll
  for (int r = 0; r < 4; r++) qr[r] = qp[l + 64 * r];
  float sc[9];
  float mx = -1e30f;
  #pragma unroll
  for (int j = 0; j <= 8; j++){
    int sj = s - j;
    bool ok = sj >= 0;
    int row = ok ? sj : 0;
    const float* kp = qkv + (size_t)row * QKVN + RDIM;
    float p = 0.f;
    #pragma unroll
    for (int r = 0; r < 4; r++) p += qr[r] * kp[l + 64 * r];
    #pragma unroll
    for (int off = 32; off; off >>= 1) p += __shfl_xor(p, off);
    p = ok ? p * 0.0625f : -1e30f;   // /sqrt(256)
    sc[j] = p;
    mx = fmaxf(mx, p);
  }
  float den = 0.f;
  #pragma unroll
  for (int j = 0; j <= 8; j++){ sc[j] = expf(sc[j] - mx); den += sc[j]; }
  float inv = 1.f / den;
  #pragma unroll
  for (int r = 0; r < 4; r++){
    float a = 0.f;
    #pragma unroll
    for (int j = 0; j <= 8; j++){
      int sj = s - j;
      int row = sj >= 0 ? sj : 0;
      a += sc[j] * qkv[(size_t)row * QKVN + 512 + l + 64 * r];
    }
    aob[(size_t)s * RDIM + l + 64 * r] = f2b(a * inv);
  }
}

// -------- chunk link ----------------------------------------------------------
__global__ void k_chunk(const float* __restrict__ xin, float* __restrict__ xout,
                        u16* __restrict__ xb){
  int s = blockIdx.x;
  int d = blockIdx.y * 256 + threadIdx.x;
  int ci = s >> 6;
  float v = xin[(size_t)s * DIM + d];
  float wsum = 1.f;
  if (ci > 0){ v += 0.5f * xin[(size_t)(s - 64) * DIM + d]; wsum += 0.5f; }
  if (ci < 63){ v += 0.5f * xin[(size_t)(s + 64) * DIM + d]; wsum += 0.5f; }
  v /= wsum;
  size_t o = (size_t)s * DIM + d;
  xout[o] = v; xb[o] = f2b(v);
}

extern "C" void kernel_launch(void* const* d_in, const int* in_sizes, int n_in,
                              void* d_out, int out_size, void* d_ws, size_t ws_size,
                              hipStream_t stream){
  const int*   idx  = (const int*)d_in[0];
  const float* emb  = (const float*)d_in[1];
  const float* pos  = (const float*)d_in[2];
  const float* Wg   = (const float*)d_in[3];
  const float* bg   = (const float*)d_in[4];
  const float* Ws_  = (const float*)d_in[5];
  const float* bs   = (const float*)d_in[6];
  const float* Wo   = (const float*)d_in[7];
  const float* bo   = (const float*)d_in[8];
  const float* Wq   = (const float*)d_in[9];
  const float* Wk   = (const float*)d_in[10];
  const float* Wv   = (const float*)d_in[11];
  const float* Wao  = (const float*)d_in[12];
  const float* bq   = (const float*)d_in[13];
  const float* bk   = (const float*)d_in[14];
  const float* bv   = (const float*)d_in[15];
  const float* bao  = (const float*)d_in[16];
  const float* outW = (const float*)d_in[17];
  const float* outb = (const float*)d_in[18];
  float* out = (float*)d_out;

  char* p = (char*)d_ws;
  auto alloc = [&](size_t n)->char*{ char* r = p; p += (n + 255) & ~(size_t)255; return r; };
  float* xfA  = (float*)alloc((size_t)S_LEN * DIM * 4);
  float* xfB  = (float*)alloc((size_t)S_LEN * DIM * 4);
  u16*   xb   = (u16*)  alloc((size_t)S_LEN * DIM * 2);
  u16*   xgb  = (u16*)  alloc((size_t)S_LEN * DIM * 2);
  u16*   tbuf = (u16*)  alloc((size_t)S_LEN * HID * 2);
  float* qkvf = (float*)alloc((size_t)S_LEN * QKVN * 4);
  u16*   aob  = (u16*)  alloc((size_t)S_LEN * RDIM * 2);
  float* bqkv2= (float*)alloc(2 * QKVN * 4);
  u16*   WgT  = (u16*)  alloc((size_t)NLAYER * DIM * DIM * 2);
  u16*   WsT  = (u16*)  alloc((size_t)NLAYER * DIM * HID * 2);
  u16*   WoT  = (u16*)  alloc((size_t)NLAYER * HID * DIM * 2);
  u16*   WqkvT= (u16*)  alloc((size_t)NLAYER * QKVN * DIM * 2);
  u16*   WaoT = (u16*)  alloc((size_t)NLAYER * RDIM * DIM * 2);
  u16*   outWT= (u16*)  alloc((size_t)VOCAB * DIM * 2);

  (void)hipFuncSetAttribute((const void*)&k_gemmL,
                      hipFuncAttributeMaxDynamicSharedMemorySize, 131072);
  (void)hipFuncSetAttribute((const void*)&k_gemm8b<EP_TANH>,
                      hipFuncAttributeMaxDynamicSharedMemorySize, 65536);
  (void)hipFuncSetAttribute((const void*)&k_gemm4<EP_GATE>,
                      hipFuncAttributeMaxDynamicSharedMemorySize, 49152);
  (void)hipFuncSetAttribute((const void*)&k_gemm4<EP_RESID>,
                      hipFuncAttributeMaxDynamicSharedMemorySize, 49152);
  (void)hipFuncSetAttribute((const void*)&k_gemm4<EP_BIASF>,
                      hipFuncAttributeMaxDynamicSharedMemorySize, 49152);
  (void)hipFuncSetAttribute((const void*)&k_gemm4<EP_AO>,
                      hipFuncAttributeMaxDynamicSharedMemorySize, 49152);

  // one prep launch: embed + all transposes + qkv bias concats
  k_prep<<<29510, dim3(16, 16), 0, stream>>>(Wg, Ws_, Wo, Wq, Wk, Wv, Wao, outW,
                                             WgT, WsT, WoT, WqkvT, WaoT, outWT,
                                             bq, bk, bv, bqkv2,
                                             idx, emb, pos, xfA, xb);

  float* curF = xfA; float* altF = xfB;
  for (int l = 0; l < NLAYER; l++){
    k_gemm4<EP_GATE ><<<(S_LEN/64)*(DIM/128),  512, 49152, stream>>>(xb,  WgT  + (size_t)l*DIM*DIM,  bg + (size_t)l*DIM, curF, nullptr, xgb, DIM, DIM, S_LEN/64, DIM/128);
    k_gemm8b<EP_TANH><<<(S_LEN/128)*(HID/128), 512, 65536, stream>>>(xgb, WsT  + (size_t)l*DIM*HID,  bs + (size_t)l*HID, nullptr, nullptr, tbuf, HID, DIM, S_LEN/128, HID/128);
    k_gemm4<EP_RESID><<<(S_LEN/64)*(DIM/128),  512, 49152, stream>>>(tbuf,WoT  + (size_t)l*HID*DIM,  bo + (size_t)l*DIM, curF, curF, xb, DIM, HID, S_LEN/64, DIM/128);
    k_gemm4<EP_BIASF><<<(S_LEN/64)*(QKVN/128), 512, 49152, stream>>>(xb,  WqkvT + (size_t)l*QKVN*DIM, bqkv2 + (size_t)l*QKVN, nullptr, qkvf, nullptr, QKVN, DIM, S_LEN/64, QKVN/128);
    k_attn<<<S_LEN/4, 256, 0, stream>>>(qkvf, aob);
    k_gemm4<EP_AO   ><<<(S_LEN/64)*(DIM/128),  512, 49152, stream>>>(aob, WaoT + (size_t)l*RDIM*DIM, bao + (size_t)l*DIM, curF, curF, nullptr, DIM, RDIM, S_LEN/64, DIM/128);
    k_chunk<<<dim3(S_LEN, DIM/256), 256, 0, stream>>>(curF, altF, xb);
    float* tmp = curF; curF = altF; altF = tmp;
  }
  k_gemmL<<<256, 512, 131072, stream>>>(xb, outWT, outb, out, VOCAB, DIM, S_LEN/256, VOCAB/256);
}